// Round 10
// baseline (130.189 us; speedup 1.0000x reference)
//
#include <hip/hip_runtime.h>
#include <hip/hip_bf16.h>

typedef __bf16 bf16x8 __attribute__((ext_vector_type(8)));
typedef __bf16 bf16x4 __attribute__((ext_vector_type(4)));
typedef float  f32x4  __attribute__((ext_vector_type(4)));

#define MFMA16(a, b, c) __builtin_amdgcn_mfma_f32_16x16x32_bf16(a, b, c, 0, 0, 0)

__device__ __forceinline__ float lrelu(float v) { return fmaxf(v, 0.01f * v); }

// ---------------------------------------------------------------------------
// prep kernels
// ---------------------------------------------------------------------------

// w1s[f][h] = sum_i linear1_w[f][i][h]   (16384 elements)
__global__ void vg_w1s(const float* __restrict__ lw1, float* __restrict__ w1s) {
  int i = blockIdx.x * 256 + threadIdx.x;
  int f = i >> 6, h = i & 63;
  w1s[i] = lw1[f * 192 + h] + lw1[f * 192 + 64 + h] + lw1[f * 192 + 128 + h];
}

// W2T[f][n(16)][k(64)] = bf16(linear2_w[f][k][n&7])  -- rows 8..15 REPLICATE
__global__ void vg_w2t(const float* __restrict__ lw2, __bf16* __restrict__ w2t) {
  int i = blockIdx.x * 256 + threadIdx.x;
  int f = i >> 10, n = (i >> 6) & 15, k = i & 63;
  w2t[i] = (__bf16)lw2[(f * 64 + k) * 8 + (n & 7)];
}

// weffT[n(256)][f*8+k] = bf16( sum_d emb[f][k][d] * pw1[(f*128+d)*256 + n] )
// (algebraic collapse: W_eff = emb @ W1, K shrinks 32768 -> 2048)
__global__ void vg_weff(const float* __restrict__ emb, const float* __restrict__ pw1,
                        __bf16* __restrict__ weffT) {
  __shared__ float es[8][128];
  const int f = blockIdx.x, n = threadIdx.x;
  for (int i = n; i < 1024; i += 256) es[i >> 7][i & 127] = emb[f * 1024 + i];
  __syncthreads();
  float s[8] = {0.f, 0.f, 0.f, 0.f, 0.f, 0.f, 0.f, 0.f};
  const float* pp = pw1 + (size_t)f * 128 * 256 + n;
#pragma unroll 4
  for (int d = 0; d < 128; d++) {
    float wv = pp[(size_t)d * 256];
#pragma unroll
    for (int k = 0; k < 8; k++) s[k] += es[k][d] * wv;
  }
  bf16x8 o;
#pragma unroll
  for (int k = 0; k < 8; k++) o[k] = (__bf16)s[k];
  *(bf16x8*)&weffT[(size_t)n * 2048 + f * 8] = o;
}

// transpose [R][C] f32 -> [C][R] bf16, 64x64 LDS tiles (for proj_w2)
__global__ void vg_transpose(const float* __restrict__ in, __bf16* __restrict__ outT,
                             int R, int C) {
  __shared__ float tile[64][65];
  int tilesPerRow = C >> 6;
  int tr = blockIdx.x / tilesPerRow, tc = blockIdx.x % tilesPerRow;
  int r0 = tr * 64, c0 = tc * 64;
  int t = threadIdx.x;
  int cc = t & 63, rq = t >> 6;
#pragma unroll 4
  for (int i = 0; i < 16; i++) {
    int rr = rq * 16 + i;
    tile[rr][cc] = in[(size_t)(r0 + rr) * C + c0 + cc];
  }
  __syncthreads();
  int rr2 = t & 63, cq = t >> 6;
#pragma unroll 4
  for (int i = 0; i < 16; i++) {
    int cc2 = cq * 16 + i;
    outT[(size_t)(c0 + cc2) * R + r0 + rr2] = (__bf16)tile[rr2][cc2];
  }
}

// ---------------------------------------------------------------------------
// main fused kernel: grid = 64 row-tiles x 16 f-groups (k-split 16 for
// 4096 waves = 16/CU), 256 thr (4 waves). Wave owns 16 rows x 16 f.
// Slabs 0-7 -> ws zpart_lo; slabs 8-15 -> d_out reused as scratch.
// ---------------------------------------------------------------------------
__global__ __launch_bounds__(256, 2) void vg_main(
    const float* __restrict__ x,      // [4096][256]
    const float* __restrict__ w1s,    // [256][64]
    const float* __restrict__ b1,     // [256][64]
    const __bf16* __restrict__ w2t,   // [256][16][64] (rows 8-15 replicas)
    const float* __restrict__ b2l,    // [256][8]
    const float* __restrict__ tau,    // [256][8]
    const __bf16* __restrict__ weffT, // [256 n][2048 k]  k = f*8+bucket
    float* __restrict__ zpart_lo,     // [8][4096][256]  groups 0-7
    float* __restrict__ zpart_hi)     // [8][4096][256]  groups 8-15 (d_out)
{
  __shared__ __align__(16) float xs[64][20];  // 16 f cols, 80B rows (16B-mult)
  __shared__ __align__(16) float ws1[1024], wb1[1024];
  __shared__ __align__(16) float wb2[128], wtau[128];

  const int g = blockIdx.x & 15;         // f-group
  const int r0 = (blockIdx.x >> 4) * 64;
  const int f0 = g * 16;
  const int t = threadIdx.x;
  const int w = t >> 6, l = t & 63, lo = l & 15, hi = l >> 4;

  for (int i = t; i < 1024; i += 256) {
    int rr = i >> 4, cc = i & 15;
    float v = x[(size_t)(r0 + rr) * 256 + f0 + cc];
    v = (v != v) ? 0.f : v;
    xs[rr][cc] = fminf(fmaxf(v, 0.f), 65536.f);
    ws1[i] = w1s[f0 * 64 + i];
    wb1[i] = b1[f0 * 64 + i];
  }
  if (t < 128) {
    wb2[t] = b2l[f0 * 8 + t];
    wtau[t] = tau[f0 * 8 + t];
  }
  __syncthreads();  // only barrier (r3 lesson)

  const int row = w * 16 + lo;

  // ---- produce paq for f-quad fq: lane hi keeps f=f0+fq*4+hi's 8 buckets
  auto produce = [&](int fq) -> bf16x8 {
    const float4 xq = *(const float4*)&xs[row][fq * 4];  // 4 subs' x in one read
    const float xr4[4] = {xq.x, xq.y, xq.z, xq.w};

    // A) 4 independent gacc chains (phase 1+2)
    f32x4 gb4[4];
#pragma unroll
    for (int sub = 0; sub < 4; sub++) {
      const int fi = fq * 4 + sub;
      const int f = f0 + fi;
      const float xr = xr4[sub];
      bf16x8 ha[2];
#pragma unroll
      for (int s = 0; s < 2; s++) {
        float4 wa = *(const float4*)(ws1 + fi * 64 + s * 32 + hi * 8);
        float4 wb = *(const float4*)(ws1 + fi * 64 + s * 32 + hi * 8 + 4);
        float4 ba = *(const float4*)(wb1 + fi * 64 + s * 32 + hi * 8);
        float4 bb = *(const float4*)(wb1 + fi * 64 + s * 32 + hi * 8 + 4);
        float hv[8];
        hv[0] = lrelu(xr * wa.x + ba.x);
        hv[1] = lrelu(xr * wa.y + ba.y);
        hv[2] = lrelu(xr * wa.z + ba.z);
        hv[3] = lrelu(xr * wa.w + ba.w);
        hv[4] = lrelu(xr * wb.x + bb.x);
        hv[5] = lrelu(xr * wb.y + bb.y);
        hv[6] = lrelu(xr * wb.z + bb.z);
        hv[7] = lrelu(xr * wb.w + bb.w);
#pragma unroll
        for (int j = 0; j < 8; j++) ha[s][j] = (__bf16)hv[j];
      }
      f32x4 gacc = {0.f, 0.f, 0.f, 0.f};
#pragma unroll
      for (int s = 0; s < 2; s++) {
        bf16x8 bw = *(const bf16x8*)&w2t[(f * 16 + lo) * 64 + s * 32 + hi * 8];
        gacc = MFMA16(bw, ha[s], gacc);
      }
      const int bidx = fi * 8 + (hi & 1) * 4;
      float4 b2v = *(const float4*)&wb2[bidx];
      float4 tv = *(const float4*)&wtau[bidx];
#pragma unroll
      for (int r = 0; r < 4; r++) gb4[sub][r] = lrelu(gacc[r] + b2v[r]) * tv[r];
    }

    // B) lockstep softmax: 4 independent chains, shfls pipelined 4-deep
    float m01[4];
#pragma unroll
    for (int sub = 0; sub < 4; sub++)
      m01[sub] = fmaxf(fmaxf(gb4[sub][0], gb4[sub][1]),
                       fmaxf(gb4[sub][2], gb4[sub][3]));
    float mx[4];
#pragma unroll
    for (int sub = 0; sub < 4; sub++)
      mx[sub] = fmaxf(m01[sub], __shfl_xor(m01[sub], 16));
    f32x4 ev4[4];
    float s4[4];
#pragma unroll
    for (int sub = 0; sub < 4; sub++) {
#pragma unroll
      for (int r = 0; r < 4; r++) ev4[sub][r] = __expf(gb4[sub][r] - mx[sub]);
      s4[sub] = (ev4[sub][0] + ev4[sub][1]) + (ev4[sub][2] + ev4[sub][3]);
    }
#pragma unroll
    for (int sub = 0; sub < 4; sub++) s4[sub] += __shfl_xor(s4[sub], 16);
    uint2 mineU[4];
#pragma unroll
    for (int sub = 0; sub < 4; sub++) {
      float inv = __builtin_amdgcn_rcpf(s4[sub]);
      bf16x4 p4;
#pragma unroll
      for (int r = 0; r < 4; r++) p4[r] = (__bf16)(ev4[sub][r] * inv);
      mineU[sub] = *(uint2*)&p4;
    }
    uint2 othU[4];
#pragma unroll
    for (int sub = 0; sub < 4; sub++) {
      othU[sub].x = __shfl_xor((int)mineU[sub].x, 16);
      othU[sub].y = __shfl_xor((int)mineU[sub].y, 16);
    }
    // C) assemble full8 per sub (bucket order 0..7 via parity), select hi's f
    bf16x8 paq = {};
#pragma unroll
    for (int sub = 0; sub < 4; sub++) {
      uint2 loU = (hi & 1) ? othU[sub] : mineU[sub];   // buckets 0..3
      uint2 hiU = (hi & 1) ? mineU[sub] : othU[sub];   // buckets 4..7
      bf16x8 f8;
      *(uint2*)&f8 = loU;
      *((uint2*)&f8 + 1) = hiU;
      if (hi == sub) paq = f8;
    }
    return paq;
  };

  f32x4 acc[16] = {};
  bf16x8 paq = produce(0);

  for (int fq = 0; fq < 4; fq++) {
    const __bf16* bp = weffT + (size_t)(f0 + fq * 4) * 8 + hi * 8;
    bf16x8 Bq[16];
#pragma unroll
    for (int n = 0; n < 16; n++)
      Bq[n] = *(const bf16x8*)&bp[(size_t)(n * 16 + lo) * 2048];

    bf16x8 paq_next = {};
    if (fq < 3) paq_next = produce(fq + 1);

#pragma unroll
    for (int n = 0; n < 16; n++) acc[n] = MFMA16(paq, Bq[n], acc[n]);
    paq = paq_next;
  }

  // write zpart slab g: wave's 16 rows x 256 cols
  float* zbase = (g < 8) ? (zpart_lo + (size_t)g * (4096 * 256))
                         : (zpart_hi + (size_t)(g - 8) * (4096 * 256));
  float* zp = zbase + (size_t)(r0 + w * 16) * 256;
#pragma unroll
  for (int n = 0; n < 16; n++)
#pragma unroll
    for (int r = 0; r < 4; r++)
      zp[(hi * 4 + r) * 256 + n * 16 + lo] = acc[n][r];
}

// ---------------------------------------------------------------------------
// z[b][n] = bf16(relu(sum over 16 slabs + b1p[n]))  (x4 vectorized)
// ---------------------------------------------------------------------------
__global__ void vg_zred(const float* __restrict__ zpart_lo,
                        const float* __restrict__ zpart_hi,
                        const float* __restrict__ b1p, __bf16* __restrict__ z) {
  int i4 = (blockIdx.x * 256 + threadIdx.x) * 4;  // 1048576 total
  float4 s = *(const float4*)&b1p[i4 & 255];
#pragma unroll
  for (int g = 0; g < 8; g++) {
    float4 v = *(const float4*)&zpart_lo[(size_t)g * 1048576 + i4];
    s.x += v.x; s.y += v.y; s.z += v.z; s.w += v.w;
  }
#pragma unroll
  for (int g = 0; g < 8; g++) {
    float4 v = *(const float4*)&zpart_hi[(size_t)g * 1048576 + i4];
    s.x += v.x; s.y += v.y; s.z += v.z; s.w += v.w;
  }
  bf16x4 o;
  o[0] = (__bf16)fmaxf(s.x, 0.f);
  o[1] = (__bf16)fmaxf(s.y, 0.f);
  o[2] = (__bf16)fmaxf(s.z, 0.f);
  o[3] = (__bf16)fmaxf(s.w, 0.f);
  *(bf16x4*)&z[i4] = o;
}

// ---------------------------------------------------------------------------
// out = z @ W2 + b2   (M=4096, N=4096, K=256)
// ---------------------------------------------------------------------------
__global__ __launch_bounds__(256, 2) void vg_out(
    const __bf16* __restrict__ z,    // [4096][256]
    const __bf16* __restrict__ w2t,  // [4096][256]  (W2T[n][k])
    const float* __restrict__ b2,    // [4096]
    float* __restrict__ out)         // [4096][4096]
{
  const int m0 = (blockIdx.x & 31) * 128;
  const int n0 = (blockIdx.x >> 5) * 128;
  const int t = threadIdx.x, w = t >> 6, l = t & 63, lo = l & 15, hi = l >> 4;
  const int wm = w >> 1, wn = w & 1;  // 2x2 waves, 64x64 each
  f32x4 acc[4][4] = {};
#pragma unroll
  for (int ks = 0; ks < 8; ks++) {
    bf16x8 A[4], Bq[4];
#pragma unroll
    for (int m = 0; m < 4; m++)
      A[m] = *(const bf16x8*)&z[(size_t)(m0 + wm * 64 + m * 16 + lo) * 256 + ks * 32 + hi * 8];
#pragma unroll
    for (int n = 0; n < 4; n++)
      Bq[n] = *(const bf16x8*)&w2t[(size_t)(n0 + wn * 64 + n * 16 + lo) * 256 + ks * 32 + hi * 8];
#pragma unroll
    for (int m = 0; m < 4; m++)
#pragma unroll
      for (int n = 0; n < 4; n++) acc[m][n] = MFMA16(A[m], Bq[n], acc[m][n]);
  }
#pragma unroll
  for (int m = 0; m < 4; m++)
#pragma unroll
    for (int n = 0; n < 4; n++) {
      int col = n0 + wn * 64 + n * 16 + lo;
      float bv = b2[col];
#pragma unroll
      for (int r = 0; r < 4; r++) {
        int row = m0 + wm * 64 + m * 16 + hi * 4 + r;
        out[(size_t)row * 4096 + col] = acc[m][n][r] + bv;
      }
    }
}

// ---------------------------------------------------------------------------
extern "C" void kernel_launch(void* const* d_in, const int* in_sizes, int n_in,
                              void* d_out, int out_size, void* d_ws, size_t ws_size,
                              hipStream_t stream) {
  const float* x   = (const float*)d_in[0];
  const float* lw1 = (const float*)d_in[1];
  const float* b1  = (const float*)d_in[2];
  const float* lw2 = (const float*)d_in[3];
  const float* b2l = (const float*)d_in[4];
  const float* tau = (const float*)d_in[5];
  const float* emb = (const float*)d_in[6];
  const float* pw1 = (const float*)d_in[7];
  const float* pb1 = (const float*)d_in[8];
  const float* pw2 = (const float*)d_in[9];
  const float* pb2 = (const float*)d_in[10];
  float* out = (float*)d_out;

  char* ws = (char*)d_ws;
  float*  w1s     = (float*)(ws + 0);         //   65536 B
  __bf16* w2t     = (__bf16*)(ws + 65536);    //  524288 B
  __bf16* weffT   = (__bf16*)(ws + 589824);   // 1048576 B
  __bf16* w2t3    = (__bf16*)(ws + 1638400);  // 2097152 B
  __bf16* z       = (__bf16*)(ws + 3735552);  // 2097152 B
  float*  zpart_lo = (float*)(ws + 5832704);  // 33554432 B (groups 0-7)
  float*  zpart_hi = out;                     // d_out reused as scratch (8-15)

  vg_w1s<<<64, 256, 0, stream>>>(lw1, w1s);
  vg_w2t<<<1024, 256, 0, stream>>>(lw2, w2t);
  vg_weff<<<256, 256, 0, stream>>>(emb, pw1, weffT);
  vg_transpose<<<256, 256, 0, stream>>>(pw2, w2t3, 256, 4096);
  vg_main<<<1024, 256, 0, stream>>>(x, w1s, b1, w2t, b2l, tau, weffT,
                                    zpart_lo, zpart_hi);
  vg_zred<<<1024, 256, 0, stream>>>(zpart_lo, zpart_hi, pb1, z);
  vg_out<<<1024, 256, 0, stream>>>(z, w2t3, pb2, out);
}

// Round 11
// 118.379 us; speedup vs baseline: 1.0998x; 1.0998x over previous
//
#include <hip/hip_runtime.h>
#include <hip/hip_bf16.h>

typedef __bf16 bf16x8 __attribute__((ext_vector_type(8)));
typedef __bf16 bf16x4 __attribute__((ext_vector_type(4)));
typedef float  f32x4  __attribute__((ext_vector_type(4)));

#define MFMA16(a, b, c) __builtin_amdgcn_mfma_f32_16x16x32_bf16(a, b, c, 0, 0, 0)

__device__ __forceinline__ float lrelu(float v) { return fmaxf(v, 0.01f * v); }

// ---------------------------------------------------------------------------
// prep kernels
// ---------------------------------------------------------------------------

// w1s[f][h] = sum_i linear1_w[f][i][h]   (16384 elements)
__global__ void vg_w1s(const float* __restrict__ lw1, float* __restrict__ w1s) {
  int i = blockIdx.x * 256 + threadIdx.x;
  int f = i >> 6, h = i & 63;
  w1s[i] = lw1[f * 192 + h] + lw1[f * 192 + 64 + h] + lw1[f * 192 + 128 + h];
}

// W2T[f][n(8)][k(64)] = bf16(linear2_w[f][k][n])   (131072, non-replicated)
__global__ void vg_w2t(const float* __restrict__ lw2, __bf16* __restrict__ w2t) {
  int i = blockIdx.x * 256 + threadIdx.x;
  int f = i >> 9, n = (i >> 6) & 7, k = i & 63;
  w2t[i] = (__bf16)lw2[(f * 64 + k) * 8 + n];
}

// weffT[n(256)][f*8+k] = bf16( sum_d emb[f][k][d] * pw1[(f*128+d)*256 + n] )
// (algebraic collapse: W_eff = emb @ W1, K shrinks 32768 -> 2048)
__global__ void vg_weff(const float* __restrict__ emb, const float* __restrict__ pw1,
                        __bf16* __restrict__ weffT) {
  __shared__ float es[8][128];
  const int f = blockIdx.x, n = threadIdx.x;
  for (int i = n; i < 1024; i += 256) es[i >> 7][i & 127] = emb[f * 1024 + i];
  __syncthreads();
  float s[8] = {0.f, 0.f, 0.f, 0.f, 0.f, 0.f, 0.f, 0.f};
  const float* pp = pw1 + (size_t)f * 128 * 256 + n;
#pragma unroll 4
  for (int d = 0; d < 128; d++) {
    float wv = pp[(size_t)d * 256];
#pragma unroll
    for (int k = 0; k < 8; k++) s[k] += es[k][d] * wv;
  }
  bf16x8 o;
#pragma unroll
  for (int k = 0; k < 8; k++) o[k] = (__bf16)s[k];
  *(bf16x8*)&weffT[(size_t)n * 2048 + f * 8] = o;
}

// transpose [R][C] f32 -> [C][R] bf16, 64x64 LDS tiles (for proj_w2)
__global__ void vg_transpose(const float* __restrict__ in, __bf16* __restrict__ outT,
                             int R, int C) {
  __shared__ float tile[64][65];
  int tilesPerRow = C >> 6;
  int tr = blockIdx.x / tilesPerRow, tc = blockIdx.x % tilesPerRow;
  int r0 = tr * 64, c0 = tc * 64;
  int t = threadIdx.x;
  int cc = t & 63, rq = t >> 6;
#pragma unroll 4
  for (int i = 0; i < 16; i++) {
    int rr = rq * 16 + i;
    tile[rr][cc] = in[(size_t)(r0 + rr) * C + c0 + cc];
  }
  __syncthreads();
  int rr2 = t & 63, cq = t >> 6;
#pragma unroll 4
  for (int i = 0; i < 16; i++) {
    int cc2 = cq * 16 + i;
    outT[(size_t)(c0 + cc2) * R + r0 + rr2] = (__bf16)tile[rr2][cc2];
  }
}

// ---------------------------------------------------------------------------
// main fused kernel: grid = 64 row-tiles x 16 f-groups, 256 thr (4 waves).
// Wave owns 16 rows x 16 f. Produce is 100% LDS-fed (w2t staged at init),
// Bq issued at iter top (covered by produce), 2-chain softmax.
// ---------------------------------------------------------------------------
__global__ __launch_bounds__(256, 2) void vg_main(
    const float* __restrict__ x,      // [4096][256]
    const float* __restrict__ w1s,    // [256][64]
    const float* __restrict__ b1,     // [256][64]
    const __bf16* __restrict__ w2t,   // [256][8][64] non-replicated
    const float* __restrict__ b2l,    // [256][8]
    const float* __restrict__ tau,    // [256][8]
    const __bf16* __restrict__ weffT, // [256 n][2048 k]  k = f*8+bucket
    float* __restrict__ zpart_lo,     // [8][4096][256]  groups 0-7
    float* __restrict__ zpart_hi)     // [8][4096][256]  groups 8-15 (d_out)
{
  __shared__ __align__(16) float xs[64][20];       // 80B rows (16B mult)
  __shared__ __align__(16) float ws1[1024], wb1[1024];
  __shared__ __align__(16) float wb2[128], wtau[128];
  __shared__ __align__(16) __bf16 w2l[128 * 72];   // 16f x 8n rows, pad->72

  const int g = blockIdx.x & 15;         // f-group
  const int r0 = (blockIdx.x >> 4) * 64;
  const int f0 = g * 16;
  const int t = threadIdx.x;
  const int w = t >> 6, l = t & 63, lo = l & 15, hi = l >> 4;

  for (int i = t; i < 1024; i += 256) {
    int rr = i >> 4, cc = i & 15;
    float v = x[(size_t)(r0 + rr) * 256 + f0 + cc];
    v = (v != v) ? 0.f : v;
    xs[rr][cc] = fminf(fmaxf(v, 0.f), 65536.f);
    ws1[i] = w1s[f0 * 64 + i];
    wb1[i] = b1[f0 * 64 + i];
  }
  // stage w2t slice (16 f x 8 n x 64 k) with padded row stride 72
  {
    const __bf16* src = w2t + (size_t)f0 * 512;
    for (int c = t; c < 1024; c += 256) {
      int r = c >> 3, j = c & 7;
      *(bf16x8*)&w2l[r * 72 + j * 8] = *(const bf16x8*)&src[r * 64 + j * 8];
    }
  }
  if (t < 128) {
    wb2[t] = b2l[f0 * 8 + t];
    wtau[t] = tau[f0 * 8 + t];
  }
  __syncthreads();  // init visible (r3 lesson); only barrier

  const int row = w * 16 + lo;
  const int lo7 = lo & 7;  // replica row for w2l A-fragment

  // ---- produce paq for f-quad fq (LDS-only inputs)
  auto produce = [&](int fq) -> bf16x8 {
    const float4 xq = *(const float4*)&xs[row][fq * 4];
    const float xr4[4] = {xq.x, xq.y, xq.z, xq.w};

    // A) 4 gacc chains (phase 1+2), w2 frags from LDS
    f32x4 gacc4[4];
#pragma unroll
    for (int sub = 0; sub < 4; sub++) {
      const int fi = fq * 4 + sub;
      const float xr = xr4[sub];
      bf16x8 ha[2];
#pragma unroll
      for (int s = 0; s < 2; s++) {
        float4 wa = *(const float4*)(ws1 + fi * 64 + s * 32 + hi * 8);
        float4 wb = *(const float4*)(ws1 + fi * 64 + s * 32 + hi * 8 + 4);
        float4 ba = *(const float4*)(wb1 + fi * 64 + s * 32 + hi * 8);
        float4 bb = *(const float4*)(wb1 + fi * 64 + s * 32 + hi * 8 + 4);
        float hv[8];
        hv[0] = lrelu(xr * wa.x + ba.x);
        hv[1] = lrelu(xr * wa.y + ba.y);
        hv[2] = lrelu(xr * wa.z + ba.z);
        hv[3] = lrelu(xr * wa.w + ba.w);
        hv[4] = lrelu(xr * wb.x + bb.x);
        hv[5] = lrelu(xr * wb.y + bb.y);
        hv[6] = lrelu(xr * wb.z + bb.z);
        hv[7] = lrelu(xr * wb.w + bb.w);
#pragma unroll
        for (int j = 0; j < 8; j++) ha[s][j] = (__bf16)hv[j];
      }
      f32x4 gacc = {0.f, 0.f, 0.f, 0.f};
#pragma unroll
      for (int s = 0; s < 2; s++) {
        bf16x8 bw = *(const bf16x8*)&w2l[(fi * 8 + lo7) * 72 + s * 32 + hi * 8];
        gacc = MFMA16(bw, ha[s], gacc);
      }
      gacc4[sub] = gacc;
    }

    // B) 2-chain softmax: lane handles pair {sA, sA+1}, sA = fq*4 + (hi&2)
    const int hb = hi & 1;
    const bool j2 = (hi & 2) != 0;
    f32x4 gA = j2 ? gacc4[2] : gacc4[0];
    f32x4 gB = j2 ? gacc4[3] : gacc4[1];
    const int sA = fq * 4 + (hi & 2);
    const float4 b2A = *(const float4*)&wb2[sA * 8 + hb * 4];
    const float4 tvA = *(const float4*)&wtau[sA * 8 + hb * 4];
    const float4 b2B = *(const float4*)&wb2[(sA + 1) * 8 + hb * 4];
    const float4 tvB = *(const float4*)&wtau[(sA + 1) * 8 + hb * 4];
    float gbA[4], gbB[4];
    gbA[0] = lrelu(gA[0] + b2A.x) * tvA.x;
    gbA[1] = lrelu(gA[1] + b2A.y) * tvA.y;
    gbA[2] = lrelu(gA[2] + b2A.z) * tvA.z;
    gbA[3] = lrelu(gA[3] + b2A.w) * tvA.w;
    gbB[0] = lrelu(gB[0] + b2B.x) * tvB.x;
    gbB[1] = lrelu(gB[1] + b2B.y) * tvB.y;
    gbB[2] = lrelu(gB[2] + b2B.z) * tvB.z;
    gbB[3] = lrelu(gB[3] + b2B.w) * tvB.w;
    float mA = fmaxf(fmaxf(gbA[0], gbA[1]), fmaxf(gbA[2], gbA[3]));
    float mB = fmaxf(fmaxf(gbB[0], gbB[1]), fmaxf(gbB[2], gbB[3]));
    mA = fmaxf(mA, __shfl_xor(mA, 16));
    mB = fmaxf(mB, __shfl_xor(mB, 16));
    float evA[4], evB[4];
#pragma unroll
    for (int r = 0; r < 4; r++) {
      evA[r] = __expf(gbA[r] - mA);
      evB[r] = __expf(gbB[r] - mB);
    }
    float sA4 = (evA[0] + evA[1]) + (evA[2] + evA[3]);
    float sB4 = (evB[0] + evB[1]) + (evB[2] + evB[3]);
    sA4 += __shfl_xor(sA4, 16);
    sB4 += __shfl_xor(sB4, 16);
    const float invA = __builtin_amdgcn_rcpf(sA4);
    const float invB = __builtin_amdgcn_rcpf(sB4);
    bf16x4 pA, pB;
#pragma unroll
    for (int r = 0; r < 4; r++) {
      pA[r] = (__bf16)(evA[r] * invA);
      pB[r] = (__bf16)(evB[r] * invB);
    }
    uint2 mineA = *(uint2*)&pA, mineB = *(uint2*)&pB;
    uint2 othA, othB;
    othA.x = __shfl_xor((int)mineA.x, 16);
    othB.x = __shfl_xor((int)mineB.x, 16);
    othA.y = __shfl_xor((int)mineA.y, 16);
    othB.y = __shfl_xor((int)mineB.y, 16);
    // assemble full8 for both f's of the pair, keep f = hi (parity hb)
    uint2 loU = hb ? (hb ? othB : othA) : mineA;  // see select below
    // explicit: fullA = {hb? othA:mineA , hb? mineA:othA}; fullB analog
    uint2 fAlo = hb ? othA : mineA, fAhi = hb ? mineA : othA;
    uint2 fBlo = hb ? othB : mineB, fBhi = hb ? mineB : othB;
    bf16x8 paq;
    *(uint2*)&paq       = hb ? fBlo : fAlo;
    *((uint2*)&paq + 1) = hb ? fBhi : fAhi;
    (void)loU;
    return paq;
  };

  f32x4 acc[16] = {};
  bf16x8 paq = produce(0);

  for (int fq = 0; fq < 4; fq++) {
    // issue all 16 B loads first; latency covered by produce(fq+1)
    const __bf16* bp = weffT + (size_t)(f0 + fq * 4) * 8 + hi * 8;
    bf16x8 Bq[16];
#pragma unroll
    for (int n = 0; n < 16; n++)
      Bq[n] = *(const bf16x8*)&bp[(size_t)(n * 16 + lo) * 2048];

    bf16x8 paq_next = {};
    if (fq < 3) paq_next = produce(fq + 1);

#pragma unroll
    for (int n = 0; n < 16; n++) acc[n] = MFMA16(paq, Bq[n], acc[n]);
    paq = paq_next;
  }

  // write zpart slab g: wave's 16 rows x 256 cols
  float* zbase = (g < 8) ? (zpart_lo + (size_t)g * (4096 * 256))
                         : (zpart_hi + (size_t)(g - 8) * (4096 * 256));
  float* zp = zbase + (size_t)(r0 + w * 16) * 256;
#pragma unroll
  for (int n = 0; n < 16; n++)
#pragma unroll
    for (int r = 0; r < 4; r++)
      zp[(hi * 4 + r) * 256 + n * 16 + lo] = acc[n][r];
}

// ---------------------------------------------------------------------------
// z[b][n] = bf16(relu(sum over 16 slabs + b1p[n]))  (x4 vectorized)
// ---------------------------------------------------------------------------
__global__ void vg_zred(const float* __restrict__ zpart_lo,
                        const float* __restrict__ zpart_hi,
                        const float* __restrict__ b1p, __bf16* __restrict__ z) {
  int i4 = (blockIdx.x * 256 + threadIdx.x) * 4;  // 1048576 total
  float4 s = *(const float4*)&b1p[i4 & 255];
#pragma unroll
  for (int g = 0; g < 8; g++) {
    float4 v = *(const float4*)&zpart_lo[(size_t)g * 1048576 + i4];
    s.x += v.x; s.y += v.y; s.z += v.z; s.w += v.w;
  }
#pragma unroll
  for (int g = 0; g < 8; g++) {
    float4 v = *(const float4*)&zpart_hi[(size_t)g * 1048576 + i4];
    s.x += v.x; s.y += v.y; s.z += v.z; s.w += v.w;
  }
  bf16x4 o;
  o[0] = (__bf16)fmaxf(s.x, 0.f);
  o[1] = (__bf16)fmaxf(s.y, 0.f);
  o[2] = (__bf16)fmaxf(s.z, 0.f);
  o[3] = (__bf16)fmaxf(s.w, 0.f);
  *(bf16x4*)&z[i4] = o;
}

// ---------------------------------------------------------------------------
// out = z @ W2 + b2   (M=4096, N=4096, K=256)
// ---------------------------------------------------------------------------
__global__ __launch_bounds__(256, 2) void vg_out(
    const __bf16* __restrict__ z,    // [4096][256]
    const __bf16* __restrict__ w2t,  // [4096][256]  (W2T[n][k])
    const float* __restrict__ b2,    // [4096]
    float* __restrict__ out)         // [4096][4096]
{
  const int m0 = (blockIdx.x & 31) * 128;
  const int n0 = (blockIdx.x >> 5) * 128;
  const int t = threadIdx.x, w = t >> 6, l = t & 63, lo = l & 15, hi = l >> 4;
  const int wm = w >> 1, wn = w & 1;  // 2x2 waves, 64x64 each
  f32x4 acc[4][4] = {};
#pragma unroll
  for (int ks = 0; ks < 8; ks++) {
    bf16x8 A[4], Bq[4];
#pragma unroll
    for (int m = 0; m < 4; m++)
      A[m] = *(const bf16x8*)&z[(size_t)(m0 + wm * 64 + m * 16 + lo) * 256 + ks * 32 + hi * 8];
#pragma unroll
    for (int n = 0; n < 4; n++)
      Bq[n] = *(const bf16x8*)&w2t[(size_t)(n0 + wn * 64 + n * 16 + lo) * 256 + ks * 32 + hi * 8];
#pragma unroll
    for (int m = 0; m < 4; m++)
#pragma unroll
      for (int n = 0; n < 4; n++) acc[m][n] = MFMA16(A[m], Bq[n], acc[m][n]);
  }
#pragma unroll
  for (int m = 0; m < 4; m++)
#pragma unroll
    for (int n = 0; n < 4; n++) {
      int col = n0 + wn * 64 + n * 16 + lo;
      float bv = b2[col];
#pragma unroll
      for (int r = 0; r < 4; r++) {
        int row = m0 + wm * 64 + m * 16 + hi * 4 + r;
        out[(size_t)row * 4096 + col] = acc[m][n][r] + bv;
      }
    }
}

// ---------------------------------------------------------------------------
extern "C" void kernel_launch(void* const* d_in, const int* in_sizes, int n_in,
                              void* d_out, int out_size, void* d_ws, size_t ws_size,
                              hipStream_t stream) {
  const float* x   = (const float*)d_in[0];
  const float* lw1 = (const float*)d_in[1];
  const float* b1  = (const float*)d_in[2];
  const float* lw2 = (const float*)d_in[3];
  const float* b2l = (const float*)d_in[4];
  const float* tau = (const float*)d_in[5];
  const float* emb = (const float*)d_in[6];
  const float* pw1 = (const float*)d_in[7];
  const float* pb1 = (const float*)d_in[8];
  const float* pw2 = (const float*)d_in[9];
  const float* pb2 = (const float*)d_in[10];
  float* out = (float*)d_out;

  char* ws = (char*)d_ws;
  float*  w1s     = (float*)(ws + 0);         //   65536 B
  __bf16* w2t     = (__bf16*)(ws + 65536);    //  262144 B used
  __bf16* weffT   = (__bf16*)(ws + 589824);   // 1048576 B
  __bf16* w2t3    = (__bf16*)(ws + 1638400);  // 2097152 B
  __bf16* z       = (__bf16*)(ws + 3735552);  // 2097152 B
  float*  zpart_lo = (float*)(ws + 5832704);  // 33554432 B (groups 0-7)
  float*  zpart_hi = out;                     // d_out reused as scratch (8-15)

  vg_w1s<<<64, 256, 0, stream>>>(lw1, w1s);
  vg_w2t<<<512, 256, 0, stream>>>(lw2, w2t);
  vg_weff<<<256, 256, 0, stream>>>(emb, pw1, weffT);
  vg_transpose<<<256, 256, 0, stream>>>(pw2, w2t3, 256, 4096);
  vg_main<<<1024, 256, 0, stream>>>(x, w1s, b1, w2t, b2l, tau, weffT,
                                    zpart_lo, zpart_hi);
  vg_zred<<<1024, 256, 0, stream>>>(zpart_lo, zpart_hi, pb1, z);
  vg_out<<<1024, 256, 0, stream>>>(z, w2t3, pb2, out);
}

// Round 12
// 98.893 us; speedup vs baseline: 1.3165x; 1.1970x over previous
//
#include <hip/hip_runtime.h>
#include <hip/hip_bf16.h>

typedef __bf16 bf16x8 __attribute__((ext_vector_type(8)));
typedef __bf16 bf16x4 __attribute__((ext_vector_type(4)));
typedef float  f32x4  __attribute__((ext_vector_type(4)));

#define MFMA16(a, b, c) __builtin_amdgcn_mfma_f32_16x16x32_bf16(a, b, c, 0, 0, 0)

__device__ __forceinline__ float lrelu(float v) { return fmaxf(v, 0.01f * v); }

// ---------------------------------------------------------------------------
// prep kernels
// ---------------------------------------------------------------------------

// w1s[f][h] = sum_i linear1_w[f][i][h]   (16384 elements)
__global__ void vg_w1s(const float* __restrict__ lw1, float* __restrict__ w1s) {
  int i = blockIdx.x * 256 + threadIdx.x;
  int f = i >> 6, h = i & 63;
  w1s[i] = lw1[f * 192 + h] + lw1[f * 192 + 64 + h] + lw1[f * 192 + 128 + h];
}

// W2T[f][n(8)][k(64)] = bf16(linear2_w[f][k][n])   (131072, non-replicated)
__global__ void vg_w2t(const float* __restrict__ lw2, __bf16* __restrict__ w2t) {
  int i = blockIdx.x * 256 + threadIdx.x;
  int f = i >> 9, n = (i >> 6) & 7, k = i & 63;
  w2t[i] = (__bf16)lw2[(f * 64 + k) * 8 + n];
}

// weffQ[q(64)][n(256)][k(32)] , q=f>>2, k=(f&3)*8+bucket
//   = bf16( sum_d emb[f][bucket][d] * pw1[(f*128+d)*256 + n] )
// Coalesced B-operand layout: a wave's 16-lane lo-span is 1KB contiguous.
__global__ void vg_weff(const float* __restrict__ emb, const float* __restrict__ pw1,
                        __bf16* __restrict__ weffQ) {
  __shared__ float es[8][128];
  const int f = blockIdx.x, n = threadIdx.x;
  for (int i = n; i < 1024; i += 256) es[i >> 7][i & 127] = emb[f * 1024 + i];
  __syncthreads();
  float s[8] = {0.f, 0.f, 0.f, 0.f, 0.f, 0.f, 0.f, 0.f};
  const float* pp = pw1 + (size_t)f * 128 * 256 + n;
#pragma unroll 4
  for (int d = 0; d < 128; d++) {
    float wv = pp[(size_t)d * 256];
#pragma unroll
    for (int k = 0; k < 8; k++) s[k] += es[k][d] * wv;
  }
  bf16x8 o;
#pragma unroll
  for (int k = 0; k < 8; k++) o[k] = (__bf16)s[k];
  *(bf16x8*)&weffQ[((size_t)(f >> 2) * 256 + n) * 32 + (f & 3) * 8] = o;
}

// transpose [R][C] f32 -> [C][R] bf16, 64x64 LDS tiles (for proj_w2)
__global__ void vg_transpose(const float* __restrict__ in, __bf16* __restrict__ outT,
                             int R, int C) {
  __shared__ float tile[64][65];
  int tilesPerRow = C >> 6;
  int tr = blockIdx.x / tilesPerRow, tc = blockIdx.x % tilesPerRow;
  int r0 = tr * 64, c0 = tc * 64;
  int t = threadIdx.x;
  int cc = t & 63, rq = t >> 6;
#pragma unroll 4
  for (int i = 0; i < 16; i++) {
    int rr = rq * 16 + i;
    tile[rr][cc] = in[(size_t)(r0 + rr) * C + c0 + cc];
  }
  __syncthreads();
  int rr2 = t & 63, cq = t >> 6;
#pragma unroll 4
  for (int i = 0; i < 16; i++) {
    int cc2 = cq * 16 + i;
    outT[(size_t)(c0 + cc2) * R + r0 + rr2] = (__bf16)tile[rr2][cc2];
  }
}

// ---------------------------------------------------------------------------
// main fused kernel: grid = 64 row-tiles x 16 f-groups, 256 thr (4 waves).
// Wave owns 16 rows x 16 f. LDS-fed produce, coalesced weffQ Bq loads,
// 2-chain softmax, f16 zpart slabs.
// ---------------------------------------------------------------------------
__global__ __launch_bounds__(256, 2) void vg_main(
    const float* __restrict__ x,      // [4096][256]
    const float* __restrict__ w1s,    // [256][64]
    const float* __restrict__ b1,     // [256][64]
    const __bf16* __restrict__ w2t,   // [256][8][64] non-replicated
    const float* __restrict__ b2l,    // [256][8]
    const float* __restrict__ tau,    // [256][8]
    const __bf16* __restrict__ weffQ, // [64][256][32]
    _Float16* __restrict__ zpart)     // [16][4096][256] f16
{
  __shared__ __align__(16) float xs[64][20];       // 80B rows (16B mult)
  __shared__ __align__(16) float ws1[1024], wb1[1024];
  __shared__ __align__(16) float wb2[128], wtau[128];
  __shared__ __align__(16) __bf16 w2l[128 * 72];   // 16f x 8n rows, pad->72

  const int g = blockIdx.x & 15;         // f-group
  const int r0 = (blockIdx.x >> 4) * 64;
  const int f0 = g * 16;
  const int t = threadIdx.x;
  const int w = t >> 6, l = t & 63, lo = l & 15, hi = l >> 4;

  for (int i = t; i < 1024; i += 256) {
    int rr = i >> 4, cc = i & 15;
    float v = x[(size_t)(r0 + rr) * 256 + f0 + cc];
    v = (v != v) ? 0.f : v;
    xs[rr][cc] = fminf(fmaxf(v, 0.f), 65536.f);
    ws1[i] = w1s[f0 * 64 + i];
    wb1[i] = b1[f0 * 64 + i];
  }
  // stage w2t slice (16 f x 8 n x 64 k) with padded row stride 72
  {
    const __bf16* src = w2t + (size_t)f0 * 512;
    for (int c = t; c < 1024; c += 256) {
      int r = c >> 3, j = c & 7;
      *(bf16x8*)&w2l[r * 72 + j * 8] = *(const bf16x8*)&src[r * 64 + j * 8];
    }
  }
  if (t < 128) {
    wb2[t] = b2l[f0 * 8 + t];
    wtau[t] = tau[f0 * 8 + t];
  }
  __syncthreads();  // init visible (r3 lesson); only barrier

  const int row = w * 16 + lo;
  const int lo7 = lo & 7;  // replica row for w2l A-fragment

  // ---- produce paq for f-quad fq (LDS-only inputs)
  auto produce = [&](int fq) -> bf16x8 {
    const float4 xq = *(const float4*)&xs[row][fq * 4];
    const float xr4[4] = {xq.x, xq.y, xq.z, xq.w};

    // A) 4 gacc chains (phase 1+2), w2 frags from LDS
    f32x4 gacc4[4];
#pragma unroll
    for (int sub = 0; sub < 4; sub++) {
      const int fi = fq * 4 + sub;
      const float xr = xr4[sub];
      bf16x8 ha[2];
#pragma unroll
      for (int s = 0; s < 2; s++) {
        float4 wa = *(const float4*)(ws1 + fi * 64 + s * 32 + hi * 8);
        float4 wb = *(const float4*)(ws1 + fi * 64 + s * 32 + hi * 8 + 4);
        float4 ba = *(const float4*)(wb1 + fi * 64 + s * 32 + hi * 8);
        float4 bb = *(const float4*)(wb1 + fi * 64 + s * 32 + hi * 8 + 4);
        float hv[8];
        hv[0] = lrelu(xr * wa.x + ba.x);
        hv[1] = lrelu(xr * wa.y + ba.y);
        hv[2] = lrelu(xr * wa.z + ba.z);
        hv[3] = lrelu(xr * wa.w + ba.w);
        hv[4] = lrelu(xr * wb.x + bb.x);
        hv[5] = lrelu(xr * wb.y + bb.y);
        hv[6] = lrelu(xr * wb.z + bb.z);
        hv[7] = lrelu(xr * wb.w + bb.w);
#pragma unroll
        for (int j = 0; j < 8; j++) ha[s][j] = (__bf16)hv[j];
      }
      f32x4 gacc = {0.f, 0.f, 0.f, 0.f};
#pragma unroll
      for (int s = 0; s < 2; s++) {
        bf16x8 bw = *(const bf16x8*)&w2l[(fi * 8 + lo7) * 72 + s * 32 + hi * 8];
        gacc = MFMA16(bw, ha[s], gacc);
      }
      gacc4[sub] = gacc;
    }

    // B) 2-chain softmax: lane handles pair {sA, sA+1}, sA = fq*4 + (hi&2)
    const int hb = hi & 1;
    const bool j2 = (hi & 2) != 0;
    f32x4 gA = j2 ? gacc4[2] : gacc4[0];
    f32x4 gB = j2 ? gacc4[3] : gacc4[1];
    const int sA = fq * 4 + (hi & 2);
    const float4 b2A = *(const float4*)&wb2[sA * 8 + hb * 4];
    const float4 tvA = *(const float4*)&wtau[sA * 8 + hb * 4];
    const float4 b2B = *(const float4*)&wb2[(sA + 1) * 8 + hb * 4];
    const float4 tvB = *(const float4*)&wtau[(sA + 1) * 8 + hb * 4];
    float gbA[4], gbB[4];
    gbA[0] = lrelu(gA[0] + b2A.x) * tvA.x;
    gbA[1] = lrelu(gA[1] + b2A.y) * tvA.y;
    gbA[2] = lrelu(gA[2] + b2A.z) * tvA.z;
    gbA[3] = lrelu(gA[3] + b2A.w) * tvA.w;
    gbB[0] = lrelu(gB[0] + b2B.x) * tvB.x;
    gbB[1] = lrelu(gB[1] + b2B.y) * tvB.y;
    gbB[2] = lrelu(gB[2] + b2B.z) * tvB.z;
    gbB[3] = lrelu(gB[3] + b2B.w) * tvB.w;
    float mA = fmaxf(fmaxf(gbA[0], gbA[1]), fmaxf(gbA[2], gbA[3]));
    float mB = fmaxf(fmaxf(gbB[0], gbB[1]), fmaxf(gbB[2], gbB[3]));
    mA = fmaxf(mA, __shfl_xor(mA, 16));
    mB = fmaxf(mB, __shfl_xor(mB, 16));
    float evA[4], evB[4];
#pragma unroll
    for (int r = 0; r < 4; r++) {
      evA[r] = __expf(gbA[r] - mA);
      evB[r] = __expf(gbB[r] - mB);
    }
    float sA4 = (evA[0] + evA[1]) + (evA[2] + evA[3]);
    float sB4 = (evB[0] + evB[1]) + (evB[2] + evB[3]);
    sA4 += __shfl_xor(sA4, 16);
    sB4 += __shfl_xor(sB4, 16);
    const float invA = __builtin_amdgcn_rcpf(sA4);
    const float invB = __builtin_amdgcn_rcpf(sB4);
    bf16x4 pA, pB;
#pragma unroll
    for (int r = 0; r < 4; r++) {
      pA[r] = (__bf16)(evA[r] * invA);
      pB[r] = (__bf16)(evB[r] * invB);
    }
    uint2 mineA = *(uint2*)&pA, mineB = *(uint2*)&pB;
    uint2 othA, othB;
    othA.x = __shfl_xor((int)mineA.x, 16);
    othB.x = __shfl_xor((int)mineB.x, 16);
    othA.y = __shfl_xor((int)mineA.y, 16);
    othB.y = __shfl_xor((int)mineB.y, 16);
    // fullA = {hb? othA:mineA , hb? mineA:othA}; fullB analog; keep f = hi
    uint2 fAlo = hb ? othA : mineA, fAhi = hb ? mineA : othA;
    uint2 fBlo = hb ? othB : mineB, fBhi = hb ? mineB : othB;
    bf16x8 paq;
    *(uint2*)&paq       = hb ? fBlo : fAlo;
    *((uint2*)&paq + 1) = hb ? fBhi : fAhi;
    return paq;
  };

  f32x4 acc[16] = {};
  bf16x8 paq = produce(0);

  for (int fq = 0; fq < 4; fq++) {
    // issue all 16 B loads first (coalesced 1KB spans); covered by produce
    const __bf16* bp = weffQ + (size_t)(g * 4 + fq) * 8192;
    bf16x8 Bq[16];
#pragma unroll
    for (int n = 0; n < 16; n++)
      Bq[n] = *(const bf16x8*)&bp[(n * 16 + lo) * 32 + hi * 8];

    bf16x8 paq_next = {};
    if (fq < 3) paq_next = produce(fq + 1);

#pragma unroll
    for (int n = 0; n < 16; n++) acc[n] = MFMA16(paq, Bq[n], acc[n]);
    paq = paq_next;
  }

  // write zpart slab g (f16): wave's 16 rows x 256 cols
  _Float16* zp = zpart + (size_t)g * (4096 * 256) + (size_t)(r0 + w * 16) * 256;
#pragma unroll
  for (int n = 0; n < 16; n++)
#pragma unroll
    for (int r = 0; r < 4; r++)
      zp[(hi * 4 + r) * 256 + n * 16 + lo] = (_Float16)acc[n][r];
}

// ---------------------------------------------------------------------------
// z[b][n] = bf16(relu(sum over 16 f16 slabs + b1p[n]))  (x8 vectorized)
// ---------------------------------------------------------------------------
__global__ void vg_zred(const _Float16* __restrict__ zpart,
                        const float* __restrict__ b1p, __bf16* __restrict__ z) {
  int i8 = (blockIdx.x * 256 + threadIdx.x) * 8;  // 1048576 total
  float s[8];
  {
    float4 ba = *(const float4*)&b1p[i8 & 255];
    float4 bb = *(const float4*)&b1p[(i8 & 255) + 4];
    s[0] = ba.x; s[1] = ba.y; s[2] = ba.z; s[3] = ba.w;
    s[4] = bb.x; s[5] = bb.y; s[6] = bb.z; s[7] = bb.w;
  }
#pragma unroll
  for (int g = 0; g < 16; g++) {
    uint4 v = *(const uint4*)&zpart[(size_t)g * 1048576 + i8];
    const _Float16* hp = (const _Float16*)&v;
#pragma unroll
    for (int j = 0; j < 8; j++) s[j] += (float)hp[j];
  }
  bf16x8 o;
#pragma unroll
  for (int j = 0; j < 8; j++) o[j] = (__bf16)fmaxf(s[j], 0.f);
  *(bf16x8*)&z[i8] = o;
}

// ---------------------------------------------------------------------------
// out = z @ W2 + b2   (M=4096, N=4096, K=256)
// ---------------------------------------------------------------------------
__global__ __launch_bounds__(256, 2) void vg_out(
    const __bf16* __restrict__ z,    // [4096][256]
    const __bf16* __restrict__ w2t,  // [4096][256]  (W2T[n][k])
    const float* __restrict__ b2,    // [4096]
    float* __restrict__ out)         // [4096][4096]
{
  const int m0 = (blockIdx.x & 31) * 128;
  const int n0 = (blockIdx.x >> 5) * 128;
  const int t = threadIdx.x, w = t >> 6, l = t & 63, lo = l & 15, hi = l >> 4;
  const int wm = w >> 1, wn = w & 1;  // 2x2 waves, 64x64 each
  f32x4 acc[4][4] = {};
#pragma unroll
  for (int ks = 0; ks < 8; ks++) {
    bf16x8 A[4], Bq[4];
#pragma unroll
    for (int m = 0; m < 4; m++)
      A[m] = *(const bf16x8*)&z[(size_t)(m0 + wm * 64 + m * 16 + lo) * 256 + ks * 32 + hi * 8];
#pragma unroll
    for (int n = 0; n < 4; n++)
      Bq[n] = *(const bf16x8*)&w2t[(size_t)(n0 + wn * 64 + n * 16 + lo) * 256 + ks * 32 + hi * 8];
#pragma unroll
    for (int m = 0; m < 4; m++)
#pragma unroll
      for (int n = 0; n < 4; n++) acc[m][n] = MFMA16(A[m], Bq[n], acc[m][n]);
  }
#pragma unroll
  for (int m = 0; m < 4; m++)
#pragma unroll
    for (int n = 0; n < 4; n++) {
      int col = n0 + wn * 64 + n * 16 + lo;
      float bv = b2[col];
#pragma unroll
      for (int r = 0; r < 4; r++) {
        int row = m0 + wm * 64 + m * 16 + hi * 4 + r;
        out[(size_t)row * 4096 + col] = acc[m][n][r] + bv;
      }
    }
}

// ---------------------------------------------------------------------------
extern "C" void kernel_launch(void* const* d_in, const int* in_sizes, int n_in,
                              void* d_out, int out_size, void* d_ws, size_t ws_size,
                              hipStream_t stream) {
  const float* x   = (const float*)d_in[0];
  const float* lw1 = (const float*)d_in[1];
  const float* b1  = (const float*)d_in[2];
  const float* lw2 = (const float*)d_in[3];
  const float* b2l = (const float*)d_in[4];
  const float* tau = (const float*)d_in[5];
  const float* emb = (const float*)d_in[6];
  const float* pw1 = (const float*)d_in[7];
  const float* pb1 = (const float*)d_in[8];
  const float* pw2 = (const float*)d_in[9];
  const float* pb2 = (const float*)d_in[10];
  float* out = (float*)d_out;

  char* ws = (char*)d_ws;
  float*  w1s   = (float*)(ws + 0);           //   65536 B
  __bf16* w2t   = (__bf16*)(ws + 65536);      //  262144 B
  __bf16* weffQ = (__bf16*)(ws + 589824);     // 1048576 B
  __bf16* w2t3  = (__bf16*)(ws + 1638400);    // 2097152 B
  __bf16* z     = (__bf16*)(ws + 3735552);    // 2097152 B
  _Float16* zpart = (_Float16*)(ws + 5832704); // 33554432 B f16 (16 slabs)

  vg_w1s<<<64, 256, 0, stream>>>(lw1, w1s);
  vg_w2t<<<512, 256, 0, stream>>>(lw2, w2t);
  vg_weff<<<256, 256, 0, stream>>>(emb, pw1, weffQ);
  vg_transpose<<<256, 256, 0, stream>>>(pw2, w2t3, 256, 4096);
  vg_main<<<1024, 256, 0, stream>>>(x, w1s, b1, w2t, b2l, tau, weffQ, zpart);
  vg_zred<<<512, 256, 0, stream>>>(zpart, pb1, z);
  vg_out<<<1024, 256, 0, stream>>>(z, w2t3, pb2, out);
}

// Round 13
// 89.257 us; speedup vs baseline: 1.4586x; 1.1080x over previous
//
#include <hip/hip_runtime.h>
#include <hip/hip_bf16.h>

typedef __bf16 bf16x8 __attribute__((ext_vector_type(8)));
typedef __bf16 bf16x4 __attribute__((ext_vector_type(4)));
typedef float  f32x4  __attribute__((ext_vector_type(4)));
typedef _Float16 f16x8 __attribute__((ext_vector_type(8)));
typedef _Float16 f16x4 __attribute__((ext_vector_type(4)));

#define MFMA16(a, b, c) __builtin_amdgcn_mfma_f32_16x16x32_bf16(a, b, c, 0, 0, 0)

__device__ __forceinline__ float lrelu(float v) { return fmaxf(v, 0.01f * v); }

// ---------------------------------------------------------------------------
// fused prep kernel: blocks 0-63 w1s/b1->f16 ; 64-575 w2t ; 576-831 transpose
// ---------------------------------------------------------------------------
__global__ void vg_prep(const float* __restrict__ lw1, const float* __restrict__ b1,
                        const float* __restrict__ lw2, const float* __restrict__ pw2,
                        _Float16* __restrict__ w1sh, _Float16* __restrict__ b1h,
                        __bf16* __restrict__ w2t, __bf16* __restrict__ w2t3) {
  __shared__ float tile[64][65];
  const int b = blockIdx.x, t = threadIdx.x;
  if (b < 64) {
    int i = b * 256 + t;
    int f = i >> 6, h = i & 63;
    w1sh[i] = (_Float16)(lw1[f * 192 + h] + lw1[f * 192 + 64 + h] +
                         lw1[f * 192 + 128 + h]);
    b1h[i] = (_Float16)b1[f * 64 + h];
  } else if (b < 576) {
    int i = (b - 64) * 256 + t;
    int f = i >> 9, n = (i >> 6) & 7, k = i & 63;
    w2t[i] = (__bf16)lw2[(f * 64 + k) * 8 + n];
  } else {
    // transpose pw2 [256][4096] f32 -> w2t3 [4096][256] bf16
    const int bb = b - 576;           // 256 blocks: 4 row-tiles x 64 col-tiles
    const int tr = bb >> 6, tc = bb & 63;
    const int r0 = tr * 64, c0 = tc * 64;
    const int cc = t & 63, rq = t >> 6;
#pragma unroll 4
    for (int i = 0; i < 16; i++) {
      int rr = rq * 16 + i;
      tile[rr][cc] = pw2[(size_t)(r0 + rr) * 4096 + c0 + cc];
    }
    __syncthreads();
    const int rr2 = t & 63, cq = t >> 6;
#pragma unroll 4
    for (int i = 0; i < 16; i++) {
      int cc2 = cq * 16 + i;
      w2t3[(size_t)(c0 + cc2) * 256 + r0 + rr2] = (__bf16)tile[rr2][cc2];
    }
  }
}

// weffQ[q(64)][n(256)][k(32)] , q=f>>2, k=(f&3)*8+bucket  (d-split x2)
__global__ __launch_bounds__(512) void vg_weff(const float* __restrict__ emb,
                                               const float* __restrict__ pw1,
                                               __bf16* __restrict__ weffQ) {
  __shared__ float es[8][128];
  __shared__ float red[256][8];
  const int f = blockIdx.x;
  const int t = threadIdx.x, n = t & 255, dh = t >> 8;
  for (int i = t; i < 1024; i += 512) es[i >> 7][i & 127] = emb[f * 1024 + i];
  __syncthreads();
  float s[8] = {0.f, 0.f, 0.f, 0.f, 0.f, 0.f, 0.f, 0.f};
  const float* pp = pw1 + (size_t)f * 32768 + (size_t)dh * 64 * 256 + n;
#pragma unroll 8
  for (int d = 0; d < 64; d++) {
    float wv = pp[(size_t)d * 256];
#pragma unroll
    for (int k = 0; k < 8; k++) s[k] += es[k][dh * 64 + d] * wv;
  }
  if (dh) {
#pragma unroll
    for (int k = 0; k < 8; k++) red[n][k] = s[k];
  }
  __syncthreads();
  if (!dh) {
    bf16x8 o;
#pragma unroll
    for (int k = 0; k < 8; k++) o[k] = (__bf16)(s[k] + red[n][k]);
    *(bf16x8*)&weffQ[((size_t)(f >> 2) * 256 + n) * 32 + (f & 3) * 8] = o;
  }
}

// ---------------------------------------------------------------------------
// main fused kernel: grid = 64 row-tiles x 16 f-groups, 256 thr (4 waves).
// Wave owns 16 rows x 16 f. f16-packed phase-1 weights (half the LDS reads),
// LDS-fed produce, coalesced weffQ Bq, 2-chain softmax, f16 zpart.
// ---------------------------------------------------------------------------
__global__ __launch_bounds__(256, 2) void vg_main(
    const float* __restrict__ x,      // [4096][256]
    const _Float16* __restrict__ w1sh,// [256][64] f16
    const _Float16* __restrict__ b1h, // [256][64] f16
    const __bf16* __restrict__ w2t,   // [256][8][64] non-replicated
    const float* __restrict__ b2l,    // [256][8]
    const float* __restrict__ tau,    // [256][8]
    const __bf16* __restrict__ weffQ, // [64][256][32]
    _Float16* __restrict__ zpart)     // [16][4096][256] f16
{
  __shared__ __align__(16) float xs[64][20];       // 80B rows (16B mult)
  __shared__ __align__(16) _Float16 ws1h[1024], wb1h[1024];
  __shared__ __align__(16) float wb2[128], wtau[128];
  __shared__ __align__(16) __bf16 w2l[128 * 72];   // 16f x 8n rows, pad->72

  const int g = blockIdx.x & 15;         // f-group
  const int r0 = (blockIdx.x >> 4) * 64;
  const int f0 = g * 16;
  const int t = threadIdx.x;
  const int w = t >> 6, l = t & 63, lo = l & 15, hi = l >> 4;

  for (int i = t; i < 1024; i += 256) {
    int rr = i >> 4, cc = i & 15;
    float v = x[(size_t)(r0 + rr) * 256 + f0 + cc];
    v = (v != v) ? 0.f : v;
    xs[rr][cc] = fminf(fmaxf(v, 0.f), 65536.f);
  }
  // f16 weight stages (each thread copies one f16x4 = 8B)
  *(f16x4*)&ws1h[t * 4] = *(const f16x4*)&w1sh[f0 * 64 + t * 4];
  *(f16x4*)&wb1h[t * 4] = *(const f16x4*)&b1h[f0 * 64 + t * 4];
  // stage w2t slice (16 f x 8 n x 64 k) with padded row stride 72
  {
    const __bf16* src = w2t + (size_t)f0 * 512;
    for (int c = t; c < 1024; c += 256) {
      int r = c >> 3, j = c & 7;
      *(bf16x8*)&w2l[r * 72 + j * 8] = *(const bf16x8*)&src[r * 64 + j * 8];
    }
  }
  if (t < 128) {
    wb2[t] = b2l[f0 * 8 + t];
    wtau[t] = tau[f0 * 8 + t];
  }
  __syncthreads();  // init visible (r3 lesson); only barrier

  const int row = w * 16 + lo;
  const int lo7 = lo & 7;  // replica row for w2l A-fragment

  // ---- produce paq for f-quad fq (LDS-only inputs)
  auto produce = [&](int fq) -> bf16x8 {
    const float4 xq = *(const float4*)&xs[row][fq * 4];
    const float xr4[4] = {xq.x, xq.y, xq.z, xq.w};

    // A) 4 gacc chains (phase 1+2), f16 weight frags from LDS
    f32x4 gacc4[4];
#pragma unroll
    for (int sub = 0; sub < 4; sub++) {
      const int fi = fq * 4 + sub;
      const float xr = xr4[sub];
      bf16x8 ha[2];
#pragma unroll
      for (int s = 0; s < 2; s++) {
        f16x8 wv = *(const f16x8*)(ws1h + fi * 64 + s * 32 + hi * 8);
        f16x8 bv = *(const f16x8*)(wb1h + fi * 64 + s * 32 + hi * 8);
#pragma unroll
        for (int j = 0; j < 8; j++) {
          float hv = lrelu(xr * (float)wv[j] + (float)bv[j]);
          ha[s][j] = (__bf16)hv;
        }
      }
      f32x4 gacc = {0.f, 0.f, 0.f, 0.f};
#pragma unroll
      for (int s = 0; s < 2; s++) {
        bf16x8 bw = *(const bf16x8*)&w2l[(fi * 8 + lo7) * 72 + s * 32 + hi * 8];
        gacc = MFMA16(bw, ha[s], gacc);
      }
      gacc4[sub] = gacc;
    }

    // B) 2-chain softmax: lane handles pair {sA, sA+1}, sA = fq*4 + (hi&2)
    const int hb = hi & 1;
    const bool j2 = (hi & 2) != 0;
    f32x4 gA = j2 ? gacc4[2] : gacc4[0];
    f32x4 gB = j2 ? gacc4[3] : gacc4[1];
    const int sA = fq * 4 + (hi & 2);
    const float4 b2A = *(const float4*)&wb2[sA * 8 + hb * 4];
    const float4 tvA = *(const float4*)&wtau[sA * 8 + hb * 4];
    const float4 b2B = *(const float4*)&wb2[(sA + 1) * 8 + hb * 4];
    const float4 tvB = *(const float4*)&wtau[(sA + 1) * 8 + hb * 4];
    float gbA[4], gbB[4];
    gbA[0] = lrelu(gA[0] + b2A.x) * tvA.x;
    gbA[1] = lrelu(gA[1] + b2A.y) * tvA.y;
    gbA[2] = lrelu(gA[2] + b2A.z) * tvA.z;
    gbA[3] = lrelu(gA[3] + b2A.w) * tvA.w;
    gbB[0] = lrelu(gB[0] + b2B.x) * tvB.x;
    gbB[1] = lrelu(gB[1] + b2B.y) * tvB.y;
    gbB[2] = lrelu(gB[2] + b2B.z) * tvB.z;
    gbB[3] = lrelu(gB[3] + b2B.w) * tvB.w;
    float mA = fmaxf(fmaxf(gbA[0], gbA[1]), fmaxf(gbA[2], gbA[3]));
    float mB = fmaxf(fmaxf(gbB[0], gbB[1]), fmaxf(gbB[2], gbB[3]));
    mA = fmaxf(mA, __shfl_xor(mA, 16));
    mB = fmaxf(mB, __shfl_xor(mB, 16));
    float evA[4], evB[4];
#pragma unroll
    for (int r = 0; r < 4; r++) {
      evA[r] = __expf(gbA[r] - mA);
      evB[r] = __expf(gbB[r] - mB);
    }
    float sA4 = (evA[0] + evA[1]) + (evA[2] + evA[3]);
    float sB4 = (evB[0] + evB[1]) + (evB[2] + evB[3]);
    sA4 += __shfl_xor(sA4, 16);
    sB4 += __shfl_xor(sB4, 16);
    const float invA = __builtin_amdgcn_rcpf(sA4);
    const float invB = __builtin_amdgcn_rcpf(sB4);
    bf16x4 pA, pB;
#pragma unroll
    for (int r = 0; r < 4; r++) {
      pA[r] = (__bf16)(evA[r] * invA);
      pB[r] = (__bf16)(evB[r] * invB);
    }
    uint2 mineA = *(uint2*)&pA, mineB = *(uint2*)&pB;
    uint2 othA, othB;
    othA.x = __shfl_xor((int)mineA.x, 16);
    othB.x = __shfl_xor((int)mineB.x, 16);
    othA.y = __shfl_xor((int)mineA.y, 16);
    othB.y = __shfl_xor((int)mineB.y, 16);
    // fullA = {hb? othA:mineA , hb? mineA:othA}; fullB analog; keep f = hi
    uint2 fAlo = hb ? othA : mineA, fAhi = hb ? mineA : othA;
    uint2 fBlo = hb ? othB : mineB, fBhi = hb ? mineB : othB;
    bf16x8 paq;
    *(uint2*)&paq       = hb ? fBlo : fAlo;
    *((uint2*)&paq + 1) = hb ? fBhi : fAhi;
    return paq;
  };

  f32x4 acc[16] = {};
  bf16x8 paq = produce(0);

  for (int fq = 0; fq < 4; fq++) {
    // issue all 16 B loads first (coalesced 1KB spans); covered by produce
    const __bf16* bp = weffQ + (size_t)(g * 4 + fq) * 8192;
    bf16x8 Bq[16];
#pragma unroll
    for (int n = 0; n < 16; n++)
      Bq[n] = *(const bf16x8*)&bp[(n * 16 + lo) * 32 + hi * 8];

    bf16x8 paq_next = {};
    if (fq < 3) paq_next = produce(fq + 1);

#pragma unroll
    for (int n = 0; n < 16; n++) acc[n] = MFMA16(paq, Bq[n], acc[n]);
    paq = paq_next;
  }

  // write zpart slab g (f16): wave's 16 rows x 256 cols
  _Float16* zp = zpart + (size_t)g * (4096 * 256) + (size_t)(r0 + w * 16) * 256;
#pragma unroll
  for (int n = 0; n < 16; n++)
#pragma unroll
    for (int r = 0; r < 4; r++)
      zp[(hi * 4 + r) * 256 + n * 16 + lo] = (_Float16)acc[n][r];
}

// ---------------------------------------------------------------------------
// z[b][n] = bf16(relu(sum over 16 f16 slabs + b1p[n]))  (x8 vectorized)
// ---------------------------------------------------------------------------
__global__ void vg_zred(const _Float16* __restrict__ zpart,
                        const float* __restrict__ b1p, __bf16* __restrict__ z) {
  int i8 = (blockIdx.x * 256 + threadIdx.x) * 8;  // 1048576 total
  float s[8];
  {
    float4 ba = *(const float4*)&b1p[i8 & 255];
    float4 bb = *(const float4*)&b1p[(i8 & 255) + 4];
    s[0] = ba.x; s[1] = ba.y; s[2] = ba.z; s[3] = ba.w;
    s[4] = bb.x; s[5] = bb.y; s[6] = bb.z; s[7] = bb.w;
  }
#pragma unroll
  for (int g = 0; g < 16; g++) {
    uint4 v = *(const uint4*)&zpart[(size_t)g * 1048576 + i8];
    const _Float16* hp = (const _Float16*)&v;
#pragma unroll
    for (int j = 0; j < 8; j++) s[j] += (float)hp[j];
  }
  bf16x8 o;
#pragma unroll
  for (int j = 0; j < 8; j++) o[j] = (__bf16)fmaxf(s[j], 0.f);
  *(bf16x8*)&z[i8] = o;
}

// ---------------------------------------------------------------------------
// out = z @ W2 + b2   (M=4096, N=4096, K=256)
// ---------------------------------------------------------------------------
__global__ __launch_bounds__(256, 2) void vg_out(
    const __bf16* __restrict__ z,    // [4096][256]
    const __bf16* __restrict__ w2t,  // [4096][256]  (W2T[n][k])
    const float* __restrict__ b2,    // [4096]
    float* __restrict__ out)         // [4096][4096]
{
  const int m0 = (blockIdx.x & 31) * 128;
  const int n0 = (blockIdx.x >> 5) * 128;
  const int t = threadIdx.x, w = t >> 6, l = t & 63, lo = l & 15, hi = l >> 4;
  const int wm = w >> 1, wn = w & 1;  // 2x2 waves, 64x64 each
  f32x4 acc[4][4] = {};
#pragma unroll
  for (int ks = 0; ks < 8; ks++) {
    bf16x8 A[4], Bq[4];
#pragma unroll
    for (int m = 0; m < 4; m++)
      A[m] = *(const bf16x8*)&z[(size_t)(m0 + wm * 64 + m * 16 + lo) * 256 + ks * 32 + hi * 8];
#pragma unroll
    for (int n = 0; n < 4; n++)
      Bq[n] = *(const bf16x8*)&w2t[(size_t)(n0 + wn * 64 + n * 16 + lo) * 256 + ks * 32 + hi * 8];
#pragma unroll
    for (int m = 0; m < 4; m++)
#pragma unroll
      for (int n = 0; n < 4; n++) acc[m][n] = MFMA16(A[m], Bq[n], acc[m][n]);
  }
#pragma unroll
  for (int m = 0; m < 4; m++)
#pragma unroll
    for (int n = 0; n < 4; n++) {
      int col = n0 + wn * 64 + n * 16 + lo;
      float bv = b2[col];
#pragma unroll
      for (int r = 0; r < 4; r++) {
        int row = m0 + wm * 64 + m * 16 + hi * 4 + r;
        out[(size_t)row * 4096 + col] = acc[m][n][r] + bv;
      }
    }
}

// ---------------------------------------------------------------------------
extern "C" void kernel_launch(void* const* d_in, const int* in_sizes, int n_in,
                              void* d_out, int out_size, void* d_ws, size_t ws_size,
                              hipStream_t stream) {
  const float* x   = (const float*)d_in[0];
  const float* lw1 = (const float*)d_in[1];
  const float* b1  = (const float*)d_in[2];
  const float* lw2 = (const float*)d_in[3];
  const float* b2l = (const float*)d_in[4];
  const float* tau = (const float*)d_in[5];
  const float* emb = (const float*)d_in[6];
  const float* pw1 = (const float*)d_in[7];
  const float* pb1 = (const float*)d_in[8];
  const float* pw2 = (const float*)d_in[9];
  const float* pb2 = (const float*)d_in[10];
  float* out = (float*)d_out;

  char* ws = (char*)d_ws;
  _Float16* w1sh = (_Float16*)(ws + 0);        //   32768 B
  _Float16* b1h  = (_Float16*)(ws + 32768);    //   32768 B
  __bf16* w2t    = (__bf16*)(ws + 65536);      //  262144 B
  __bf16* weffQ  = (__bf16*)(ws + 589824);     // 1048576 B
  __bf16* w2t3   = (__bf16*)(ws + 1638400);    // 2097152 B
  __bf16* z      = (__bf16*)(ws + 3735552);    // 2097152 B
  _Float16* zpart = (_Float16*)(ws + 5832704); // 33554432 B f16 (16 slabs)

  vg_prep<<<832, 256, 0, stream>>>(lw1, b1, lw2, pw2, w1sh, b1h, w2t, w2t3);
  vg_weff<<<256, 512, 0, stream>>>(emb, pw1, weffQ);
  vg_main<<<1024, 256, 0, stream>>>(x, w1sh, b1h, w2t, b2l, tau, weffQ, zpart);
  vg_zred<<<512, 256, 0, stream>>>(zpart, pb1, z);
  vg_out<<<1024, 256, 0, stream>>>(z, w2t3, pb2, out);
}

// Round 14
// 84.820 us; speedup vs baseline: 1.5349x; 1.0523x over previous
//
#include <hip/hip_runtime.h>
#include <hip/hip_bf16.h>

typedef __bf16 bf16x8 __attribute__((ext_vector_type(8)));
typedef __bf16 bf16x4 __attribute__((ext_vector_type(4)));
typedef float  f32x4  __attribute__((ext_vector_type(4)));
typedef _Float16 f16x8 __attribute__((ext_vector_type(8)));
typedef _Float16 f16x4 __attribute__((ext_vector_type(4)));

#define MFMA16(a, b, c) __builtin_amdgcn_mfma_f32_16x16x32_bf16(a, b, c, 0, 0, 0)

__device__ __forceinline__ float lrelu(float v) { return fmaxf(v, 0.01f * v); }

// ---------------------------------------------------------------------------
// fused prep kernel: blocks 0-63 w1s/b1->f16 ; 64-575 w2t ; 576-831 transpose
// pw2 transpose now emits FRAGMENT-MAJOR w2f[nb][ks][lo*4+hi][8]
// ---------------------------------------------------------------------------
__global__ void vg_prep(const float* __restrict__ lw1, const float* __restrict__ b1,
                        const float* __restrict__ lw2, const float* __restrict__ pw2,
                        _Float16* __restrict__ w1sh, _Float16* __restrict__ b1h,
                        __bf16* __restrict__ w2t, __bf16* __restrict__ w2f) {
  __shared__ float tile[64][65];
  const int b = blockIdx.x, t = threadIdx.x;
  if (b < 64) {
    int i = b * 256 + t;
    int f = i >> 6, h = i & 63;
    w1sh[i] = (_Float16)(lw1[f * 192 + h] + lw1[f * 192 + 64 + h] +
                         lw1[f * 192 + 128 + h]);
    b1h[i] = (_Float16)b1[f * 64 + h];
  } else if (b < 576) {
    int i = (b - 64) * 256 + t;
    int f = i >> 9, n = (i >> 6) & 7, k = i & 63;
    w2t[i] = (__bf16)lw2[(f * 64 + k) * 8 + n];
  } else {
    // pw2 [256 k][4096 col] f32 -> w2f fragment-major bf16
    const int bb = b - 576;           // 256 blocks: 4 k-tiles x 64 col-tiles
    const int tr = bb >> 6, tc = bb & 63;
    const int r0 = tr * 64, c0 = tc * 64;
    const int cc = t & 63, rq = t >> 6;
#pragma unroll 4
    for (int i = 0; i < 16; i++) {
      int rr = rq * 16 + i;
      tile[rr][cc] = pw2[(size_t)(r0 + rr) * 4096 + c0 + cc];
    }
    __syncthreads();
    const int rr2 = t & 63, cq = t >> 6;
    const int k = r0 + rr2;
#pragma unroll 4
    for (int i = 0; i < 16; i++) {
      int cc2 = cq * 16 + i;
      int col = c0 + cc2;
      int idx = (((col >> 4) * 8 + (k >> 5)) * 64 + (col & 15) * 4 +
                 ((k >> 3) & 3)) * 8 + (k & 7);
      w2f[idx] = (__bf16)tile[rr2][cc2];
    }
  }
}

// weffQ[q(64)][n(256)][k(32)] , q=f>>2, k=(f&3)*8+bucket  (d-split x2)
__global__ __launch_bounds__(512) void vg_weff(const float* __restrict__ emb,
                                               const float* __restrict__ pw1,
                                               __bf16* __restrict__ weffQ) {
  __shared__ float es[8][128];
  __shared__ float red[256][8];
  const int f = blockIdx.x;
  const int t = threadIdx.x, n = t & 255, dh = t >> 8;
  for (int i = t; i < 1024; i += 512) es[i >> 7][i & 127] = emb[f * 1024 + i];
  __syncthreads();
  float s[8] = {0.f, 0.f, 0.f, 0.f, 0.f, 0.f, 0.f, 0.f};
  const float* pp = pw1 + (size_t)f * 32768 + (size_t)dh * 64 * 256 + n;
#pragma unroll 8
  for (int d = 0; d < 64; d++) {
    float wv = pp[(size_t)d * 256];
#pragma unroll
    for (int k = 0; k < 8; k++) s[k] += es[k][dh * 64 + d] * wv;
  }
  if (dh) {
#pragma unroll
    for (int k = 0; k < 8; k++) red[n][k] = s[k];
  }
  __syncthreads();
  if (!dh) {
    bf16x8 o;
#pragma unroll
    for (int k = 0; k < 8; k++) o[k] = (__bf16)(s[k] + red[n][k]);
    *(bf16x8*)&weffQ[((size_t)(f >> 2) * 256 + n) * 32 + (f & 3) * 8] = o;
  }
}

// ---------------------------------------------------------------------------
// main fused kernel: grid = 64 row-tiles x 16 f-groups, 256 thr (4 waves).
// ---------------------------------------------------------------------------
__global__ __launch_bounds__(256, 2) void vg_main(
    const float* __restrict__ x,      // [4096][256]
    const _Float16* __restrict__ w1sh,// [256][64] f16
    const _Float16* __restrict__ b1h, // [256][64] f16
    const __bf16* __restrict__ w2t,   // [256][8][64] non-replicated
    const float* __restrict__ b2l,    // [256][8]
    const float* __restrict__ tau,    // [256][8]
    const __bf16* __restrict__ weffQ, // [64][256][32]
    _Float16* __restrict__ zpart)     // [16][4096][256] f16
{
  __shared__ __align__(16) float xs[64][20];       // 80B rows (16B mult)
  __shared__ __align__(16) _Float16 ws1h[1024], wb1h[1024];
  __shared__ __align__(16) float wb2[128], wtau[128];
  __shared__ __align__(16) __bf16 w2l[128 * 72];   // 16f x 8n rows, pad->72

  const int g = blockIdx.x & 15;         // f-group
  const int r0 = (blockIdx.x >> 4) * 64;
  const int f0 = g * 16;
  const int t = threadIdx.x;
  const int w = t >> 6, l = t & 63, lo = l & 15, hi = l >> 4;

  for (int i = t; i < 1024; i += 256) {
    int rr = i >> 4, cc = i & 15;
    float v = x[(size_t)(r0 + rr) * 256 + f0 + cc];
    v = (v != v) ? 0.f : v;
    xs[rr][cc] = fminf(fmaxf(v, 0.f), 65536.f);
  }
  *(f16x4*)&ws1h[t * 4] = *(const f16x4*)&w1sh[f0 * 64 + t * 4];
  *(f16x4*)&wb1h[t * 4] = *(const f16x4*)&b1h[f0 * 64 + t * 4];
  {
    const __bf16* src = w2t + (size_t)f0 * 512;
    for (int c = t; c < 1024; c += 256) {
      int r = c >> 3, j = c & 7;
      *(bf16x8*)&w2l[r * 72 + j * 8] = *(const bf16x8*)&src[r * 64 + j * 8];
    }
  }
  if (t < 128) {
    wb2[t] = b2l[f0 * 8 + t];
    wtau[t] = tau[f0 * 8 + t];
  }
  __syncthreads();  // init visible (r3 lesson); only barrier

  const int row = w * 16 + lo;
  const int lo7 = lo & 7;

  auto produce = [&](int fq) -> bf16x8 {
    const float4 xq = *(const float4*)&xs[row][fq * 4];
    const float xr4[4] = {xq.x, xq.y, xq.z, xq.w};
    f32x4 gacc4[4];
#pragma unroll
    for (int sub = 0; sub < 4; sub++) {
      const int fi = fq * 4 + sub;
      const float xr = xr4[sub];
      bf16x8 ha[2];
#pragma unroll
      for (int s = 0; s < 2; s++) {
        f16x8 wv = *(const f16x8*)(ws1h + fi * 64 + s * 32 + hi * 8);
        f16x8 bv = *(const f16x8*)(wb1h + fi * 64 + s * 32 + hi * 8);
#pragma unroll
        for (int j = 0; j < 8; j++) {
          float hv = lrelu(xr * (float)wv[j] + (float)bv[j]);
          ha[s][j] = (__bf16)hv;
        }
      }
      f32x4 gacc = {0.f, 0.f, 0.f, 0.f};
#pragma unroll
      for (int s = 0; s < 2; s++) {
        bf16x8 bw = *(const bf16x8*)&w2l[(fi * 8 + lo7) * 72 + s * 32 + hi * 8];
        gacc = MFMA16(bw, ha[s], gacc);
      }
      gacc4[sub] = gacc;
    }
    const int hb = hi & 1;
    const bool j2 = (hi & 2) != 0;
    f32x4 gA = j2 ? gacc4[2] : gacc4[0];
    f32x4 gB = j2 ? gacc4[3] : gacc4[1];
    const int sA = fq * 4 + (hi & 2);
    const float4 b2A = *(const float4*)&wb2[sA * 8 + hb * 4];
    const float4 tvA = *(const float4*)&wtau[sA * 8 + hb * 4];
    const float4 b2B = *(const float4*)&wb2[(sA + 1) * 8 + hb * 4];
    const float4 tvB = *(const float4*)&wtau[(sA + 1) * 8 + hb * 4];
    float gbA[4], gbB[4];
    gbA[0] = lrelu(gA[0] + b2A.x) * tvA.x;
    gbA[1] = lrelu(gA[1] + b2A.y) * tvA.y;
    gbA[2] = lrelu(gA[2] + b2A.z) * tvA.z;
    gbA[3] = lrelu(gA[3] + b2A.w) * tvA.w;
    gbB[0] = lrelu(gB[0] + b2B.x) * tvB.x;
    gbB[1] = lrelu(gB[1] + b2B.y) * tvB.y;
    gbB[2] = lrelu(gB[2] + b2B.z) * tvB.z;
    gbB[3] = lrelu(gB[3] + b2B.w) * tvB.w;
    float mA = fmaxf(fmaxf(gbA[0], gbA[1]), fmaxf(gbA[2], gbA[3]));
    float mB = fmaxf(fmaxf(gbB[0], gbB[1]), fmaxf(gbB[2], gbB[3]));
    mA = fmaxf(mA, __shfl_xor(mA, 16));
    mB = fmaxf(mB, __shfl_xor(mB, 16));
    float evA[4], evB[4];
#pragma unroll
    for (int r = 0; r < 4; r++) {
      evA[r] = __expf(gbA[r] - mA);
      evB[r] = __expf(gbB[r] - mB);
    }
    float sA4 = (evA[0] + evA[1]) + (evA[2] + evA[3]);
    float sB4 = (evB[0] + evB[1]) + (evB[2] + evB[3]);
    sA4 += __shfl_xor(sA4, 16);
    sB4 += __shfl_xor(sB4, 16);
    const float invA = __builtin_amdgcn_rcpf(sA4);
    const float invB = __builtin_amdgcn_rcpf(sB4);
    bf16x4 pA, pB;
#pragma unroll
    for (int r = 0; r < 4; r++) {
      pA[r] = (__bf16)(evA[r] * invA);
      pB[r] = (__bf16)(evB[r] * invB);
    }
    uint2 mineA = *(uint2*)&pA, mineB = *(uint2*)&pB;
    uint2 othA, othB;
    othA.x = __shfl_xor((int)mineA.x, 16);
    othB.x = __shfl_xor((int)mineB.x, 16);
    othA.y = __shfl_xor((int)mineA.y, 16);
    othB.y = __shfl_xor((int)mineB.y, 16);
    uint2 fAlo = hb ? othA : mineA, fAhi = hb ? mineA : othA;
    uint2 fBlo = hb ? othB : mineB, fBhi = hb ? mineB : othB;
    bf16x8 paq;
    *(uint2*)&paq       = hb ? fBlo : fAlo;
    *((uint2*)&paq + 1) = hb ? fBhi : fAhi;
    return paq;
  };

  f32x4 acc[16] = {};
  bf16x8 paq = produce(0);

  for (int fq = 0; fq < 4; fq++) {
    const __bf16* bp = weffQ + (size_t)(g * 4 + fq) * 8192;
    bf16x8 Bq[16];
#pragma unroll
    for (int n = 0; n < 16; n++)
      Bq[n] = *(const bf16x8*)&bp[(n * 16 + lo) * 32 + hi * 8];

    bf16x8 paq_next = {};
    if (fq < 3) paq_next = produce(fq + 1);

#pragma unroll
    for (int n = 0; n < 16; n++) acc[n] = MFMA16(paq, Bq[n], acc[n]);
    paq = paq_next;
  }

  _Float16* zp = zpart + (size_t)g * (4096 * 256) + (size_t)(r0 + w * 16) * 256;
#pragma unroll
  for (int n = 0; n < 16; n++)
#pragma unroll
    for (int r = 0; r < 4; r++)
      zp[(hi * 4 + r) * 256 + n * 16 + lo] = (_Float16)acc[n][r];
}

// ---------------------------------------------------------------------------
// z[b][n] = bf16(relu(sum over 16 f16 slabs + b1p[n]))
// emits FRAGMENT-MAJOR zf[rb][ks][lo*4+hi][8]
// ---------------------------------------------------------------------------
__global__ void vg_zred(const _Float16* __restrict__ zpart,
                        const float* __restrict__ b1p, __bf16* __restrict__ zf) {
  int i8 = (blockIdx.x * 256 + threadIdx.x) * 8;  // 1048576 total
  float s[8];
  {
    float4 ba = *(const float4*)&b1p[i8 & 255];
    float4 bb = *(const float4*)&b1p[(i8 & 255) + 4];
    s[0] = ba.x; s[1] = ba.y; s[2] = ba.z; s[3] = ba.w;
    s[4] = bb.x; s[5] = bb.y; s[6] = bb.z; s[7] = bb.w;
  }
#pragma unroll
  for (int g = 0; g < 16; g++) {
    uint4 v = *(const uint4*)&zpart[(size_t)g * 1048576 + i8];
    const _Float16* hp = (const _Float16*)&v;
#pragma unroll
    for (int j = 0; j < 8; j++) s[j] += (float)hp[j];
  }
  bf16x8 o;
#pragma unroll
  for (int j = 0; j < 8; j++) o[j] = (__bf16)fmaxf(s[j], 0.f);
  const int row = i8 >> 8, k0 = i8 & 255;
  const int idx = (((row >> 4) * 8 + (k0 >> 5)) * 64 + (row & 15) * 4 +
                   ((k0 >> 3) & 3)) * 8;
  *(bf16x8*)&zf[idx] = o;
}

// ---------------------------------------------------------------------------
// out = z @ W2 + b2  (fragment-major operands: every load = 1KB wave-burst)
// ---------------------------------------------------------------------------
__global__ __launch_bounds__(256, 2) void vg_out(
    const __bf16* __restrict__ zf,   // fragment-major [256 rb][8 ks][64][8]
    const __bf16* __restrict__ w2f,  // fragment-major [256 nb][8 ks][64][8]
    const float* __restrict__ b2,    // [4096]
    float* __restrict__ out)         // [4096][4096]
{
  const int m0 = (blockIdx.x & 31) * 128;
  const int n0 = (blockIdx.x >> 5) * 128;
  const int t = threadIdx.x, w = t >> 6, l = t & 63, lo = l & 15, hi = l >> 4;
  const int wm = w >> 1, wn = w & 1;  // 2x2 waves, 64x64 each
  const int fo = (lo * 4 + hi) * 8;   // fragment elem offset
  f32x4 acc[4][4] = {};
#pragma unroll
  for (int ks = 0; ks < 8; ks++) {
    bf16x8 A[4], Bq[4];
#pragma unroll
    for (int m = 0; m < 4; m++) {
      int rb = (m0 >> 4) + wm * 4 + m;
      A[m] = *(const bf16x8*)&zf[(rb * 8 + ks) * 512 + fo];
    }
#pragma unroll
    for (int n = 0; n < 4; n++) {
      int nb = (n0 >> 4) + wn * 4 + n;
      Bq[n] = *(const bf16x8*)&w2f[(nb * 8 + ks) * 512 + fo];
    }
#pragma unroll
    for (int m = 0; m < 4; m++)
#pragma unroll
      for (int n = 0; n < 4; n++) acc[m][n] = MFMA16(A[m], Bq[n], acc[m][n]);
  }
#pragma unroll
  for (int m = 0; m < 4; m++)
#pragma unroll
    for (int n = 0; n < 4; n++) {
      int col = n0 + wn * 64 + n * 16 + lo;
      float bv = b2[col];
#pragma unroll
      for (int r = 0; r < 4; r++) {
        int row = m0 + wm * 64 + m * 16 + hi * 4 + r;
        out[(size_t)row * 4096 + col] = acc[m][n][r] + bv;
      }
    }
}

// ---------------------------------------------------------------------------
extern "C" void kernel_launch(void* const* d_in, const int* in_sizes, int n_in,
                              void* d_out, int out_size, void* d_ws, size_t ws_size,
                              hipStream_t stream) {
  const float* x   = (const float*)d_in[0];
  const float* lw1 = (const float*)d_in[1];
  const float* b1  = (const float*)d_in[2];
  const float* lw2 = (const float*)d_in[3];
  const float* b2l = (const float*)d_in[4];
  const float* tau = (const float*)d_in[5];
  const float* emb = (const float*)d_in[6];
  const float* pw1 = (const float*)d_in[7];
  const float* pb1 = (const float*)d_in[8];
  const float* pw2 = (const float*)d_in[9];
  const float* pb2 = (const float*)d_in[10];
  float* out = (float*)d_out;

  char* ws = (char*)d_ws;
  _Float16* w1sh = (_Float16*)(ws + 0);        //   32768 B
  _Float16* b1h  = (_Float16*)(ws + 32768);    //   32768 B
  __bf16* w2t    = (__bf16*)(ws + 65536);      //  262144 B
  __bf16* weffQ  = (__bf16*)(ws + 589824);     // 1048576 B
  __bf16* w2f    = (__bf16*)(ws + 1638400);    // 2097152 B fragment-major
  __bf16* zf     = (__bf16*)(ws + 3735552);    // 2097152 B fragment-major
  _Float16* zpart = (_Float16*)(ws + 5832704); // 33554432 B f16 (16 slabs)

  vg_prep<<<832, 256, 0, stream>>>(lw1, b1, lw2, pw2, w1sh, b1h, w2t, w2f);
  vg_weff<<<256, 512, 0, stream>>>(emb, pw1, weffQ);
  vg_main<<<1024, 256, 0, stream>>>(x, w1sh, b1h, w2t, b2l, tau, weffQ, zpart);
  vg_zred<<<512, 256, 0, stream>>>(zpart, pb1, zf);
  vg_out<<<1024, 256, 0, stream>>>(zf, w2f, pb2, out);
}

// Round 15
// 75.279 us; speedup vs baseline: 1.7294x; 1.1267x over previous
//
#include <hip/hip_runtime.h>
#include <hip/hip_bf16.h>

typedef __bf16 bf16x8 __attribute__((ext_vector_type(8)));
typedef __bf16 bf16x4 __attribute__((ext_vector_type(4)));
typedef float  f32x4  __attribute__((ext_vector_type(4)));
typedef _Float16 f16x8 __attribute__((ext_vector_type(8)));
typedef _Float16 f16x4 __attribute__((ext_vector_type(4)));

#define MFMA16(a, b, c) __builtin_amdgcn_mfma_f32_16x16x32_bf16(a, b, c, 0, 0, 0)

__device__ __forceinline__ float lrelu(float v) { return fmaxf(v, 0.01f * v); }

// ---------------------------------------------------------------------------
// fused prep kernel (512 thr): b<32 w1s/b1->f16 ; b<288 w2t ; b<544 pw2->w2f
// fragment-major ; b<800 weff (d-split x2)
// ---------------------------------------------------------------------------
__global__ __launch_bounds__(512) void vg_prep(
    const float* __restrict__ lw1, const float* __restrict__ b1,
    const float* __restrict__ lw2, const float* __restrict__ pw2,
    const float* __restrict__ emb, const float* __restrict__ pw1,
    _Float16* __restrict__ w1sh, _Float16* __restrict__ b1h,
    __bf16* __restrict__ w2t, __bf16* __restrict__ w2f,
    __bf16* __restrict__ weffQ) {
  __shared__ float tile[64][65];  // 16640B; weff reuses as es(1024)+red(2048)
  const int b = blockIdx.x, t = threadIdx.x;
  if (b < 32) {
    int i = b * 512 + t;  // 16384
    int f = i >> 6, h = i & 63;
    w1sh[i] = (_Float16)(lw1[f * 192 + h] + lw1[f * 192 + 64 + h] +
                         lw1[f * 192 + 128 + h]);
    b1h[i] = (_Float16)b1[f * 64 + h];
  } else if (b < 288) {
    int i = (b - 32) * 512 + t;  // 131072
    int f = i >> 9, n = (i >> 6) & 7, k = i & 63;
    w2t[i] = (__bf16)lw2[(f * 64 + k) * 8 + n];
  } else if (b < 544) {
    // pw2 [256 k][4096 col] f32 -> w2f fragment-major bf16
    const int bb = b - 288;           // 256 blocks: 4 k-tiles x 64 col-tiles
    const int tr = bb >> 6, tc = bb & 63;
    const int r0 = tr * 64, c0 = tc * 64;
    const int cc = t & 63, rq = t >> 6;  // rq 0..7
#pragma unroll
    for (int i = 0; i < 8; i++) {
      int rr = rq * 8 + i;
      tile[rr][cc] = pw2[(size_t)(r0 + rr) * 4096 + c0 + cc];
    }
    __syncthreads();
    const int rr2 = t & 63, cq = t >> 6;
    const int k = r0 + rr2;
#pragma unroll
    for (int i = 0; i < 8; i++) {
      int cc2 = cq * 8 + i;
      int col = c0 + cc2;
      int idx = (((col >> 4) * 8 + (k >> 5)) * 64 + (col & 15) * 4 +
                 ((k >> 3) & 3)) * 8 + (k & 7);
      w2f[idx] = (__bf16)tile[rr2][cc2];
    }
  } else {
    // weffQ[q(64)][n(256)][k(32)], q=f>>2, k=(f&3)*8+bucket ; W_eff = emb@W1
    const int f = b - 544;
    float* es = &tile[0][0];   // [8][128]
    float* red = es + 1024;    // [256][8]
    for (int i = t; i < 1024; i += 512) es[i] = emb[f * 1024 + i];
    __syncthreads();
    const int n = t & 255, dh = t >> 8;
    float s[8] = {0.f, 0.f, 0.f, 0.f, 0.f, 0.f, 0.f, 0.f};
    const float* pp = pw1 + (size_t)f * 32768 + (size_t)dh * 64 * 256 + n;
#pragma unroll 8
    for (int d = 0; d < 64; d++) {
      float wv = pp[(size_t)d * 256];
#pragma unroll
      for (int k = 0; k < 8; k++) s[k] += es[k * 128 + dh * 64 + d] * wv;
    }
    if (dh) {
#pragma unroll
      for (int k = 0; k < 8; k++) red[n * 8 + k] = s[k];
    }
    __syncthreads();
    if (!dh) {
      bf16x8 o;
#pragma unroll
      for (int k = 0; k < 8; k++) o[k] = (__bf16)(s[k] + red[n * 8 + k]);
      *(bf16x8*)&weffQ[((size_t)(f >> 2) * 256 + n) * 32 + (f & 3) * 8] = o;
    }
  }
}

// ---------------------------------------------------------------------------
// main fused kernel: grid = 64 row-tiles x 8 f-groups (k-split 8), 256 thr.
// Wave owns 16 rows x 32 f. LDS-fed produce; 2-shfl softmax (f16 g-exchange,
// no max-sub -- |g|<~2 bounded); coalesced weffQ Bq; f16 zpart (8 slabs).
// ---------------------------------------------------------------------------
__global__ __launch_bounds__(256, 2) void vg_main(
    const float* __restrict__ x,      // [4096][256]
    const _Float16* __restrict__ w1sh,// [256][64] f16
    const _Float16* __restrict__ b1h, // [256][64] f16
    const __bf16* __restrict__ w2t,   // [256][8][64]
    const float* __restrict__ b2l,    // [256][8]
    const float* __restrict__ tau,    // [256][8]
    const __bf16* __restrict__ weffQ, // [64][256][32]
    _Float16* __restrict__ zpart)     // [8][4096][256] f16
{
  __shared__ __align__(16) float xs[64][36];       // 32 f cols + pad
  __shared__ __align__(16) _Float16 ws1h[2048], wb1h[2048];
  __shared__ __align__(16) float wb2[256], wtau[256];
  __shared__ __align__(16) __bf16 w2l[256 * 72];   // 32f x 8n rows, pad->72

  const int g = blockIdx.x & 7;          // f-group
  const int r0 = (blockIdx.x >> 3) * 64;
  const int f0 = g * 32;
  const int t = threadIdx.x;
  const int w = t >> 6, l = t & 63, lo = l & 15, hi = l >> 4;

  for (int i = t; i < 2048; i += 256) {
    int rr = i >> 5, cc = i & 31;
    float v = x[(size_t)(r0 + rr) * 256 + f0 + cc];
    v = (v != v) ? 0.f : v;
    xs[rr][cc] = fminf(fmaxf(v, 0.f), 65536.f);
  }
  *(f16x8*)&ws1h[t * 8] = *(const f16x8*)&w1sh[f0 * 64 + t * 8];
  *(f16x8*)&wb1h[t * 8] = *(const f16x8*)&b1h[f0 * 64 + t * 8];
  {
    const __bf16* src = w2t + (size_t)f0 * 512;
    for (int c = t; c < 2048; c += 256) {
      int r = c >> 3, j = c & 7;
      *(bf16x8*)&w2l[r * 72 + j * 8] = *(const bf16x8*)&src[r * 64 + j * 8];
    }
  }
  wb2[t] = b2l[f0 * 8 + t];
  wtau[t] = tau[f0 * 8 + t];
  __syncthreads();  // init visible (r3 lesson); only barrier

  const int row = w * 16 + lo;
  const int lo7 = lo & 7;

  // ---- produce paq for f-quad fq (LDS-only); lane's f = f0+fq*4+hi
  auto produce = [&](int fq) -> bf16x8 {
    const float4 xq = *(const float4*)&xs[row][fq * 4];
    const float xr4[4] = {xq.x, xq.y, xq.z, xq.w};

    // A) 4 gacc chains (phase 1+2)
    f32x4 gacc4[4];
#pragma unroll
    for (int sub = 0; sub < 4; sub++) {
      const int fi = fq * 4 + sub;
      const float xr = xr4[sub];
      bf16x8 ha[2];
#pragma unroll
      for (int s = 0; s < 2; s++) {
        f16x8 wv = *(const f16x8*)(ws1h + fi * 64 + s * 32 + hi * 8);
        f16x8 bv = *(const f16x8*)(wb1h + fi * 64 + s * 32 + hi * 8);
#pragma unroll
        for (int j = 0; j < 8; j++) {
          float hv = lrelu(xr * (float)wv[j] + (float)bv[j]);
          ha[s][j] = (__bf16)hv;
        }
      }
      f32x4 gacc = {0.f, 0.f, 0.f, 0.f};
#pragma unroll
      for (int s = 0; s < 2; s++) {
        bf16x8 bw = *(const bf16x8*)&w2l[(fi * 8 + lo7) * 72 + s * 32 + hi * 8];
        gacc = MFMA16(bw, ha[s], gacc);
      }
      gacc4[sub] = gacc;
    }

    // B) pair softmax: exchange raw g (f16-packed, 2 shfls), then full
    // 8-bucket softmax in-lane; no max-sub (|g| bounded small).
    const int hb = hi & 1;
    const bool j2 = (hi & 2) != 0;
    f32x4 gA = j2 ? gacc4[2] : gacc4[0];
    f32x4 gB = j2 ? gacc4[3] : gacc4[1];
    const int sA = fq * 4 + (hi & 2);
    const float4 b2A = *(const float4*)&wb2[sA * 8 + hb * 4];
    const float4 tvA = *(const float4*)&wtau[sA * 8 + hb * 4];
    const float4 b2B = *(const float4*)&wb2[(sA + 1) * 8 + hb * 4];
    const float4 tvB = *(const float4*)&wtau[(sA + 1) * 8 + hb * 4];
    float gbA[4], gbB[4];
    gbA[0] = lrelu(gA[0] + b2A.x) * tvA.x;
    gbA[1] = lrelu(gA[1] + b2A.y) * tvA.y;
    gbA[2] = lrelu(gA[2] + b2A.z) * tvA.z;
    gbA[3] = lrelu(gA[3] + b2A.w) * tvA.w;
    gbB[0] = lrelu(gB[0] + b2B.x) * tvB.x;
    gbB[1] = lrelu(gB[1] + b2B.y) * tvB.y;
    gbB[2] = lrelu(gB[2] + b2B.z) * tvB.z;
    gbB[3] = lrelu(gB[3] + b2B.w) * tvB.w;
    // own = my chain's local buckets; tx = partner's needed chain
    float own[4], tx[4];
#pragma unroll
    for (int r = 0; r < 4; r++) {
      own[r] = hb ? gbB[r] : gbA[r];
      tx[r] = hb ? gbA[r] : gbB[r];
    }
    f16x4 th;
#pragma unroll
    for (int r = 0; r < 4; r++) th[r] = (_Float16)tx[r];
    uint2 tu = *(uint2*)&th, ru;
    ru.x = __shfl_xor((int)tu.x, 16);
    ru.y = __shfl_xor((int)tu.y, 16);
    f16x4 rh;
    *(uint2*)&rh = ru;
    float v8[8];
#pragma unroll
    for (int r = 0; r < 4; r++) {
      v8[r]     = hb ? (float)rh[r] : own[r];  // buckets 0-3
      v8[4 + r] = hb ? own[r] : (float)rh[r];  // buckets 4-7
    }
    float e8[8];
#pragma unroll
    for (int j = 0; j < 8; j++) e8[j] = __expf(v8[j]);
    float sum = ((e8[0] + e8[1]) + (e8[2] + e8[3])) +
                ((e8[4] + e8[5]) + (e8[6] + e8[7]));
    float inv = __builtin_amdgcn_rcpf(sum);
    bf16x8 paq;
#pragma unroll
    for (int j = 0; j < 8; j++) paq[j] = (__bf16)(e8[j] * inv);
    return paq;
  };

  f32x4 acc[16] = {};
  bf16x8 paq = produce(0);

  for (int fq = 0; fq < 8; fq++) {
    // issue all 16 B loads first (coalesced 1KB spans); covered by produce
    const __bf16* bp = weffQ + (size_t)(g * 8 + fq) * 8192;
    bf16x8 Bq[16];
#pragma unroll
    for (int n = 0; n < 16; n++)
      Bq[n] = *(const bf16x8*)&bp[(n * 16 + lo) * 32 + hi * 8];

    bf16x8 paq_next = {};
    if (fq < 7) paq_next = produce(fq + 1);

#pragma unroll
    for (int n = 0; n < 16; n++) acc[n] = MFMA16(paq, Bq[n], acc[n]);
    paq = paq_next;
  }

  _Float16* zp = zpart + (size_t)g * (4096 * 256) + (size_t)(r0 + w * 16) * 256;
#pragma unroll
  for (int n = 0; n < 16; n++)
#pragma unroll
    for (int r = 0; r < 4; r++)
      zp[(hi * 4 + r) * 256 + n * 16 + lo] = (_Float16)acc[n][r];
}

// ---------------------------------------------------------------------------
// z[b][n] = bf16(relu(sum over 8 f16 slabs + b1p[n])), fragment-major out
// ---------------------------------------------------------------------------
__global__ void vg_zred(const _Float16* __restrict__ zpart,
                        const float* __restrict__ b1p, __bf16* __restrict__ zf) {
  int i8 = (blockIdx.x * 256 + threadIdx.x) * 8;  // 1048576 total
  float s[8];
  {
    float4 ba = *(const float4*)&b1p[i8 & 255];
    float4 bb = *(const float4*)&b1p[(i8 & 255) + 4];
    s[0] = ba.x; s[1] = ba.y; s[2] = ba.z; s[3] = ba.w;
    s[4] = bb.x; s[5] = bb.y; s[6] = bb.z; s[7] = bb.w;
  }
#pragma unroll
  for (int g = 0; g < 8; g++) {
    uint4 v = *(const uint4*)&zpart[(size_t)g * 1048576 + i8];
    const _Float16* hp = (const _Float16*)&v;
#pragma unroll
    for (int j = 0; j < 8; j++) s[j] += (float)hp[j];
  }
  bf16x8 o;
#pragma unroll
  for (int j = 0; j < 8; j++) o[j] = (__bf16)fmaxf(s[j], 0.f);
  const int row = i8 >> 8, k0 = i8 & 255;
  const int idx = (((row >> 4) * 8 + (k0 >> 5)) * 64 + (row & 15) * 4 +
                   ((k0 >> 3) & 3)) * 8;
  *(bf16x8*)&zf[idx] = o;
}

// ---------------------------------------------------------------------------
// out = z @ W2 + b2  (fragment-major operands: every load = 1KB wave-burst)
// ---------------------------------------------------------------------------
__global__ __launch_bounds__(256, 2) void vg_out(
    const __bf16* __restrict__ zf,   // fragment-major [256 rb][8 ks][64][8]
    const __bf16* __restrict__ w2f,  // fragment-major [256 nb][8 ks][64][8]
    const float* __restrict__ b2,    // [4096]
    float* __restrict__ out)         // [4096][4096]
{
  const int m0 = (blockIdx.x & 31) * 128;
  const int n0 = (blockIdx.x >> 5) * 128;
  const int t = threadIdx.x, w = t >> 6, l = t & 63, lo = l & 15, hi = l >> 4;
  const int wm = w >> 1, wn = w & 1;  // 2x2 waves, 64x64 each
  const int fo = (lo * 4 + hi) * 8;   // fragment elem offset
  f32x4 acc[4][4] = {};
#pragma unroll
  for (int ks = 0; ks < 8; ks++) {
    bf16x8 A[4], Bq[4];
#pragma unroll
    for (int m = 0; m < 4; m++) {
      int rb = (m0 >> 4) + wm * 4 + m;
      A[m] = *(const bf16x8*)&zf[(rb * 8 + ks) * 512 + fo];
    }
#pragma unroll
    for (int n = 0; n < 4; n++) {
      int nb = (n0 >> 4) + wn * 4 + n;
      Bq[n] = *(const bf16x8*)&w2f[(nb * 8 + ks) * 512 + fo];
    }
#pragma unroll
    for (int m = 0; m < 4; m++)
#pragma unroll
      for (int n = 0; n < 4; n++) acc[m][n] = MFMA16(A[m], Bq[n], acc[m][n]);
  }
#pragma unroll
  for (int m = 0; m < 4; m++)
#pragma unroll
    for (int n = 0; n < 4; n++) {
      int col = n0 + wn * 64 + n * 16 + lo;
      float bv = b2[col];
#pragma unroll
      for (int r = 0; r < 4; r++) {
        int row = m0 + wm * 64 + m * 16 + hi * 4 + r;
        out[(size_t)row * 4096 + col] = acc[m][n][r] + bv;
      }
    }
}

// ---------------------------------------------------------------------------
extern "C" void kernel_launch(void* const* d_in, const int* in_sizes, int n_in,
                              void* d_out, int out_size, void* d_ws, size_t ws_size,
                              hipStream_t stream) {
  const float* x   = (const float*)d_in[0];
  const float* lw1 = (const float*)d_in[1];
  const float* b1  = (const float*)d_in[2];
  const float* lw2 = (const float*)d_in[3];
  const float* b2l = (const float*)d_in[4];
  const float* tau = (const float*)d_in[5];
  const float* emb = (const float*)d_in[6];
  const float* pw1 = (const float*)d_in[7];
  const float* pb1 = (const float*)d_in[8];
  const float* pw2 = (const float*)d_in[9];
  const float* pb2 = (const float*)d_in[10];
  float* out = (float*)d_out;

  char* ws = (char*)d_ws;
  _Float16* w1sh = (_Float16*)(ws + 0);        //   32768 B
  _Float16* b1h  = (_Float16*)(ws + 32768);    //   32768 B
  __bf16* w2t    = (__bf16*)(ws + 65536);      //  262144 B
  __bf16* weffQ  = (__bf16*)(ws + 589824);     // 1048576 B
  __bf16* w2f    = (__bf16*)(ws + 1638400);    // 2097152 B fragment-major
  __bf16* zf     = (__bf16*)(ws + 3735552);    // 2097152 B fragment-major
  _Float16* zpart = (_Float16*)(ws + 5832704); // 16777216 B f16 (8 slabs)

  vg_prep<<<800, 512, 0, stream>>>(lw1, b1, lw2, pw2, emb, pw1,
                                   w1sh, b1h, w2t, w2f, weffQ);
  vg_main<<<512, 256, 0, stream>>>(x, w1sh, b1h, w2t, b2l, tau, weffQ, zpart);
  vg_zred<<<512, 256, 0, stream>>>(zpart, pb1, zf);
  vg_out<<<1024, 256, 0, stream>>>(zf, w2f, pb2, out);
}

// Round 16
// 69.394 us; speedup vs baseline: 1.8761x; 1.0848x over previous
//
#include <hip/hip_runtime.h>
#include <hip/hip_bf16.h>

typedef __bf16 bf16x8 __attribute__((ext_vector_type(8)));
typedef __bf16 bf16x4 __attribute__((ext_vector_type(4)));
typedef float  f32x4  __attribute__((ext_vector_type(4)));
typedef _Float16 f16x8 __attribute__((ext_vector_type(8)));
typedef _Float16 f16x4 __attribute__((ext_vector_type(4)));

#define MFMA16(a, b, c) __builtin_amdgcn_mfma_f32_16x16x32_bf16(a, b, c, 0, 0, 0)

__device__ __forceinline__ float lrelu(float v) { return fmaxf(v, 0.01f * v); }

// ---------------------------------------------------------------------------
// fused prep kernel (512 thr): b<32 w1s/b1->f16 ; b<288 w2t ; b<544 pw2->w2f
// fragment-major ; b<800 weff (d-split x2)
// ---------------------------------------------------------------------------
__global__ __launch_bounds__(512) void vg_prep(
    const float* __restrict__ lw1, const float* __restrict__ b1,
    const float* __restrict__ lw2, const float* __restrict__ pw2,
    const float* __restrict__ emb, const float* __restrict__ pw1,
    _Float16* __restrict__ w1sh, _Float16* __restrict__ b1h,
    __bf16* __restrict__ w2t, __bf16* __restrict__ w2f,
    __bf16* __restrict__ weffQ) {
  __shared__ float tile[64][65];  // 16640B; weff reuses as es(1024)+red(2048)
  const int b = blockIdx.x, t = threadIdx.x;
  if (b < 32) {
    int i = b * 512 + t;  // 16384
    int f = i >> 6, h = i & 63;
    w1sh[i] = (_Float16)(lw1[f * 192 + h] + lw1[f * 192 + 64 + h] +
                         lw1[f * 192 + 128 + h]);
    b1h[i] = (_Float16)b1[f * 64 + h];
  } else if (b < 288) {
    int i = (b - 32) * 512 + t;  // 131072
    int f = i >> 9, n = (i >> 6) & 7, k = i & 63;
    w2t[i] = (__bf16)lw2[(f * 64 + k) * 8 + n];
  } else if (b < 544) {
    // pw2 [256 k][4096 col] f32 -> w2f fragment-major bf16
    const int bb = b - 288;           // 256 blocks: 4 k-tiles x 64 col-tiles
    const int tr = bb >> 6, tc = bb & 63;
    const int r0 = tr * 64, c0 = tc * 64;
    const int cc = t & 63, rq = t >> 6;  // rq 0..7
#pragma unroll
    for (int i = 0; i < 8; i++) {
      int rr = rq * 8 + i;
      tile[rr][cc] = pw2[(size_t)(r0 + rr) * 4096 + c0 + cc];
    }
    __syncthreads();
    const int rr2 = t & 63, cq = t >> 6;
    const int k = r0 + rr2;
#pragma unroll
    for (int i = 0; i < 8; i++) {
      int cc2 = cq * 8 + i;
      int col = c0 + cc2;
      int idx = (((col >> 4) * 8 + (k >> 5)) * 64 + (col & 15) * 4 +
                 ((k >> 3) & 3)) * 8 + (k & 7);
      w2f[idx] = (__bf16)tile[rr2][cc2];
    }
  } else {
    // weffQ[q(64)][n(256)][k(32)], q=f>>2, k=(f&3)*8+bucket ; W_eff = emb@W1
    const int f = b - 544;
    float* es = &tile[0][0];   // [8][128]
    float* red = es + 1024;    // [256][8]
    for (int i = t; i < 1024; i += 512) es[i] = emb[f * 1024 + i];
    __syncthreads();
    const int n = t & 255, dh = t >> 8;
    float s[8] = {0.f, 0.f, 0.f, 0.f, 0.f, 0.f, 0.f, 0.f};
    const float* pp = pw1 + (size_t)f * 32768 + (size_t)dh * 64 * 256 + n;
#pragma unroll 8
    for (int d = 0; d < 64; d++) {
      float wv = pp[(size_t)d * 256];
#pragma unroll
      for (int k = 0; k < 8; k++) s[k] += es[k * 128 + dh * 64 + d] * wv;
    }
    if (dh) {
#pragma unroll
      for (int k = 0; k < 8; k++) red[n * 8 + k] = s[k];
    }
    __syncthreads();
    if (!dh) {
      bf16x8 o;
#pragma unroll
      for (int k = 0; k < 8; k++) o[k] = (__bf16)(s[k] + red[n * 8 + k]);
      *(bf16x8*)&weffQ[((size_t)(f >> 2) * 256 + n) * 32 + (f & 3) * 8] = o;
    }
  }
}

// ---------------------------------------------------------------------------
// main fused kernel: grid = 64 row-tiles x 8 f-groups (k-split 8), 256 thr.
// Wave owns 16 rows x 32 f. LDS-fed produce; 2-shfl softmax; coalesced weffQ
// Bq; SWAPPED z-GEMM (lane holds 4 consecutive cols) -> f16x4 z stores.
// ---------------------------------------------------------------------------
__global__ __launch_bounds__(256, 2) void vg_main(
    const float* __restrict__ x,      // [4096][256]
    const _Float16* __restrict__ w1sh,// [256][64] f16
    const _Float16* __restrict__ b1h, // [256][64] f16
    const __bf16* __restrict__ w2t,   // [256][8][64]
    const float* __restrict__ b2l,    // [256][8]
    const float* __restrict__ tau,    // [256][8]
    const __bf16* __restrict__ weffQ, // [64][256][32]
    _Float16* __restrict__ zpart)     // [8][4096][256] f16
{
  __shared__ __align__(16) float xs[64][36];       // 32 f cols + pad
  __shared__ __align__(16) _Float16 ws1h[2048], wb1h[2048];
  __shared__ __align__(16) float wb2[256], wtau[256];
  __shared__ __align__(16) __bf16 w2l[256 * 72];   // 32f x 8n rows, pad->72

  const int g = blockIdx.x & 7;          // f-group
  const int r0 = (blockIdx.x >> 3) * 64;
  const int f0 = g * 32;
  const int t = threadIdx.x;
  const int w = t >> 6, l = t & 63, lo = l & 15, hi = l >> 4;

  for (int i = t; i < 2048; i += 256) {
    int rr = i >> 5, cc = i & 31;
    float v = x[(size_t)(r0 + rr) * 256 + f0 + cc];
    v = (v != v) ? 0.f : v;
    xs[rr][cc] = fminf(fmaxf(v, 0.f), 65536.f);
  }
  *(f16x8*)&ws1h[t * 8] = *(const f16x8*)&w1sh[f0 * 64 + t * 8];
  *(f16x8*)&wb1h[t * 8] = *(const f16x8*)&b1h[f0 * 64 + t * 8];
  {
    const __bf16* src = w2t + (size_t)f0 * 512;
    for (int c = t; c < 2048; c += 256) {
      int r = c >> 3, j = c & 7;
      *(bf16x8*)&w2l[r * 72 + j * 8] = *(const bf16x8*)&src[r * 64 + j * 8];
    }
  }
  wb2[t] = b2l[f0 * 8 + t];
  wtau[t] = tau[f0 * 8 + t];
  __syncthreads();  // init visible (r3 lesson); only barrier

  const int row = w * 16 + lo;
  const int lo7 = lo & 7;

  // ---- produce paq for f-quad fq (LDS-only); lane's f = f0+fq*4+hi
  auto produce = [&](int fq) -> bf16x8 {
    const float4 xq = *(const float4*)&xs[row][fq * 4];
    const float xr4[4] = {xq.x, xq.y, xq.z, xq.w};

    // A) 4 gacc chains (phase 1+2)
    f32x4 gacc4[4];
#pragma unroll
    for (int sub = 0; sub < 4; sub++) {
      const int fi = fq * 4 + sub;
      const float xr = xr4[sub];
      bf16x8 ha[2];
#pragma unroll
      for (int s = 0; s < 2; s++) {
        f16x8 wv = *(const f16x8*)(ws1h + fi * 64 + s * 32 + hi * 8);
        f16x8 bv = *(const f16x8*)(wb1h + fi * 64 + s * 32 + hi * 8);
#pragma unroll
        for (int j = 0; j < 8; j++) {
          float hv = lrelu(xr * (float)wv[j] + (float)bv[j]);
          ha[s][j] = (__bf16)hv;
        }
      }
      f32x4 gacc = {0.f, 0.f, 0.f, 0.f};
#pragma unroll
      for (int s = 0; s < 2; s++) {
        bf16x8 bw = *(const bf16x8*)&w2l[(fi * 8 + lo7) * 72 + s * 32 + hi * 8];
        gacc = MFMA16(bw, ha[s], gacc);
      }
      gacc4[sub] = gacc;
    }

    // B) pair softmax: exchange raw g (f16-packed, 2 shfls), then full
    // 8-bucket softmax in-lane; no max-sub (|g| bounded small).
    const int hb = hi & 1;
    const bool j2 = (hi & 2) != 0;
    f32x4 gA = j2 ? gacc4[2] : gacc4[0];
    f32x4 gB = j2 ? gacc4[3] : gacc4[1];
    const int sA = fq * 4 + (hi & 2);
    const float4 b2A = *(const float4*)&wb2[sA * 8 + hb * 4];
    const float4 tvA = *(const float4*)&wtau[sA * 8 + hb * 4];
    const float4 b2B = *(const float4*)&wb2[(sA + 1) * 8 + hb * 4];
    const float4 tvB = *(const float4*)&wtau[(sA + 1) * 8 + hb * 4];
    float gbA[4], gbB[4];
    gbA[0] = lrelu(gA[0] + b2A.x) * tvA.x;
    gbA[1] = lrelu(gA[1] + b2A.y) * tvA.y;
    gbA[2] = lrelu(gA[2] + b2A.z) * tvA.z;
    gbA[3] = lrelu(gA[3] + b2A.w) * tvA.w;
    gbB[0] = lrelu(gB[0] + b2B.x) * tvB.x;
    gbB[1] = lrelu(gB[1] + b2B.y) * tvB.y;
    gbB[2] = lrelu(gB[2] + b2B.z) * tvB.z;
    gbB[3] = lrelu(gB[3] + b2B.w) * tvB.w;
    float own[4], tx[4];
#pragma unroll
    for (int r = 0; r < 4; r++) {
      own[r] = hb ? gbB[r] : gbA[r];
      tx[r] = hb ? gbA[r] : gbB[r];
    }
    f16x4 th;
#pragma unroll
    for (int r = 0; r < 4; r++) th[r] = (_Float16)tx[r];
    uint2 tu = *(uint2*)&th, ru;
    ru.x = __shfl_xor((int)tu.x, 16);
    ru.y = __shfl_xor((int)tu.y, 16);
    f16x4 rh;
    *(uint2*)&rh = ru;
    float v8[8];
#pragma unroll
    for (int r = 0; r < 4; r++) {
      v8[r]     = hb ? (float)rh[r] : own[r];  // buckets 0-3
      v8[4 + r] = hb ? own[r] : (float)rh[r];  // buckets 4-7
    }
    float e8[8];
#pragma unroll
    for (int j = 0; j < 8; j++) e8[j] = __expf(v8[j]);
    float sum = ((e8[0] + e8[1]) + (e8[2] + e8[3])) +
                ((e8[4] + e8[5]) + (e8[6] + e8[7]));
    float inv = __builtin_amdgcn_rcpf(sum);
    bf16x8 paq;
#pragma unroll
    for (int j = 0; j < 8; j++) paq[j] = (__bf16)(e8[j] * inv);
    return paq;
  };

  f32x4 acc[16] = {};
  bf16x8 paq = produce(0);

  for (int fq = 0; fq < 8; fq++) {
    // issue all 16 B loads first (coalesced 1KB spans); covered by produce
    const __bf16* bp = weffQ + (size_t)(g * 8 + fq) * 8192;
    bf16x8 Bq[16];
#pragma unroll
    for (int n = 0; n < 16; n++)
      Bq[n] = *(const bf16x8*)&bp[(n * 16 + lo) * 32 + hi * 8];

    bf16x8 paq_next = {};
    if (fq < 7) paq_next = produce(fq + 1);

    // SWAPPED operands: lane(lo,hi) reg r = z[row=lo][col=n*16+hi*4+r]
#pragma unroll
    for (int n = 0; n < 16; n++) acc[n] = MFMA16(Bq[n], paq, acc[n]);
    paq = paq_next;
  }

  // z store: lane writes 4 consecutive cols per n -> f16x4 (b64) stores
  _Float16* zp = zpart + (size_t)g * (4096 * 256) +
                 (size_t)(r0 + w * 16 + lo) * 256 + hi * 4;
#pragma unroll
  for (int n = 0; n < 16; n++) {
    f16x4 h;
#pragma unroll
    for (int r = 0; r < 4; r++) h[r] = (_Float16)acc[n][r];
    *(f16x4*)&zp[n * 16] = h;
  }
}

// ---------------------------------------------------------------------------
// z[b][n] = bf16(relu(sum over 8 f16 slabs + b1p[n])), fragment-major out
// ---------------------------------------------------------------------------
__global__ void vg_zred(const _Float16* __restrict__ zpart,
                        const float* __restrict__ b1p, __bf16* __restrict__ zf) {
  int i8 = (blockIdx.x * 256 + threadIdx.x) * 8;  // 1048576 total
  float s[8];
  {
    float4 ba = *(const float4*)&b1p[i8 & 255];
    float4 bb = *(const float4*)&b1p[(i8 & 255) + 4];
    s[0] = ba.x; s[1] = ba.y; s[2] = ba.z; s[3] = ba.w;
    s[4] = bb.x; s[5] = bb.y; s[6] = bb.z; s[7] = bb.w;
  }
#pragma unroll
  for (int g = 0; g < 8; g++) {
    uint4 v = *(const uint4*)&zpart[(size_t)g * 1048576 + i8];
    const _Float16* hp = (const _Float16*)&v;
#pragma unroll
    for (int j = 0; j < 8; j++) s[j] += (float)hp[j];
  }
  bf16x8 o;
#pragma unroll
  for (int j = 0; j < 8; j++) o[j] = (__bf16)fmaxf(s[j], 0.f);
  const int row = i8 >> 8, k0 = i8 & 255;
  const int idx = (((row >> 4) * 8 + (k0 >> 5)) * 64 + (row & 15) * 4 +
                   ((k0 >> 3) & 3)) * 8;
  *(bf16x8*)&zf[idx] = o;
}

// ---------------------------------------------------------------------------
// out = z @ W2 + b2 : fragment-major loads; SWAPPED MFMA so each lane holds
// 4 consecutive out-cols -> float4 (dwordx4) stores.
// ---------------------------------------------------------------------------
__global__ __launch_bounds__(256, 2) void vg_out(
    const __bf16* __restrict__ zf,   // fragment-major [256 rb][8 ks][64][8]
    const __bf16* __restrict__ w2f,  // fragment-major [256 nb][8 ks][64][8]
    const float* __restrict__ b2,    // [4096]
    float* __restrict__ out)         // [4096][4096]
{
  const int m0 = (blockIdx.x & 31) * 128;
  const int n0 = (blockIdx.x >> 5) * 128;
  const int t = threadIdx.x, w = t >> 6, l = t & 63, lo = l & 15, hi = l >> 4;
  const int wm = w >> 1, wn = w & 1;  // 2x2 waves, 64x64 each
  const int fo = (lo * 4 + hi) * 8;   // fragment elem offset
  f32x4 acc[4][4] = {};
#pragma unroll
  for (int ks = 0; ks < 8; ks++) {
    bf16x8 A[4], Bq[4];
#pragma unroll
    for (int m = 0; m < 4; m++) {
      int rb = (m0 >> 4) + wm * 4 + m;
      A[m] = *(const bf16x8*)&zf[(rb * 8 + ks) * 512 + fo];
    }
#pragma unroll
    for (int n = 0; n < 4; n++) {
      int nb = (n0 >> 4) + wn * 4 + n;
      Bq[n] = *(const bf16x8*)&w2f[(nb * 8 + ks) * 512 + fo];
    }
    // SWAPPED: lane(lo,hi) reg r = out[row=lo][col = n*16 + hi*4 + r]
#pragma unroll
    for (int m = 0; m < 4; m++)
#pragma unroll
      for (int n = 0; n < 4; n++) acc[m][n] = MFMA16(Bq[n], A[m], acc[m][n]);
  }
#pragma unroll
  for (int m = 0; m < 4; m++) {
    const int row = m0 + wm * 64 + m * 16 + lo;
#pragma unroll
    for (int n = 0; n < 4; n++) {
      const int col = n0 + wn * 64 + n * 16 + hi * 4;
      float4 bv = *(const float4*)&b2[col];
      float4 v;
      v.x = acc[m][n][0] + bv.x;
      v.y = acc[m][n][1] + bv.y;
      v.z = acc[m][n][2] + bv.z;
      v.w = acc[m][n][3] + bv.w;
      *(float4*)&out[(size_t)row * 4096 + col] = v;
    }
  }
}

// ---------------------------------------------------------------------------
extern "C" void kernel_launch(void* const* d_in, const int* in_sizes, int n_in,
                              void* d_out, int out_size, void* d_ws, size_t ws_size,
                              hipStream_t stream) {
  const float* x   = (const float*)d_in[0];
  const float* lw1 = (const float*)d_in[1];
  const float* b1  = (const float*)d_in[2];
  const float* lw2 = (const float*)d_in[3];
  const float* b2l = (const float*)d_in[4];
  const float* tau = (const float*)d_in[5];
  const float* emb = (const float*)d_in[6];
  const float* pw1 = (const float*)d_in[7];
  const float* pb1 = (const float*)d_in[8];
  const float* pw2 = (const float*)d_in[9];
  const float* pb2 = (const float*)d_in[10];
  float* out = (float*)d_out;

  char* ws = (char*)d_ws;
  _Float16* w1sh = (_Float16*)(ws + 0);        //   32768 B
  _Float16* b1h  = (_Float16*)(ws + 32768);    //   32768 B
  __bf16* w2t    = (__bf16*)(ws + 65536);      //  262144 B
  __bf16* weffQ  = (__bf16*)(ws + 589824);     // 1048576 B
  __bf16* w2f    = (__bf16*)(ws + 1638400);    // 2097152 B fragment-major
  __bf16* zf     = (__bf16*)(ws + 3735552);    // 2097152 B fragment-major
  _Float16* zpart = (_Float16*)(ws + 5832704); // 16777216 B f16 (8 slabs)

  vg_prep<<<800, 512, 0, stream>>>(lw1, b1, lw2, pw2, emb, pw1,
                                   w1sh, b1h, w2t, w2f, weffQ);
  vg_main<<<512, 256, 0, stream>>>(x, w1sh, b1h, w2t, b2l, tau, weffQ, zpart);
  vg_zred<<<512, 256, 0, stream>>>(zpart, pb1, zf);
  vg_out<<<1024, 256, 0, stream>>>(zf, w2f, pb2, out);
}